// Round 1
// baseline (175.358 us; speedup 1.0000x reference)
//
#include <hip/hip_runtime.h>
#include <hip/hip_bf16.h>
#include <math.h>

#define MTILE 64
#define NSPLIT 8

typedef __attribute__((ext_vector_type(8))) short short8;
typedef __attribute__((ext_vector_type(4))) float f32x4;

__device__ __forceinline__ short f2bf(float f) {
    __hip_bfloat16 h = __float2bfloat16(f);
    return __builtin_bit_cast(short, h);
}

// Main kernel: each block handles MTILE rows of x and one N-split chunk of X.
// Computes partial sum_j exp(d2 / (-2 b^2)) per row (no max-subtraction: all
// logits <= 0 and nearest-neighbor logit ~ -25 >> fp32 underflow).
__global__ __launch_bounds__(256) void kde_main(
    const float* __restrict__ x, const float* __restrict__ Xg,
    const float* __restrict__ bw, float* __restrict__ ws,
    float* __restrict__ out, int M, int N, int nsplit, float coeff)
{
    const int tid  = threadIdx.x;
    const int lane = tid & 63;
    const int wave = tid >> 6;
    const int l15  = lane & 15;
    const int kq   = lane >> 4;          // 0..3
    const int rowbase = blockIdx.x * MTILE;
    const int split   = blockIdx.y;
    const int chunk   = (N + nsplit - 1) / nsplit;
    const int colstart = split * chunk;
    const int colend   = min(colstart + chunk, N);

    __shared__ float lds_x2[MTILE];
    __shared__ float red[4][MTILE];

    // ---- per-row ||x||^2 into LDS (once per block) ----
    if (tid < MTILE) {
        const float* xp = x + (size_t)(rowbase + tid) * 64;
        float s = 0.f;
        #pragma unroll
        for (int k = 0; k < 16; ++k) {
            float4 v = ((const float4*)xp)[k];
            s += v.x*v.x + v.y*v.y + v.z*v.z + v.w*v.w;
        }
        lds_x2[tid] = s;
    }

    // ---- A fragments (x tile, bf16), hoisted into registers ----
    // A layout for mfma_f32_16x16x32_bf16: row = lane&15, k = 8*(lane>>4) + i
    short8 afrag[4][2];
    #pragma unroll
    for (int rf = 0; rf < 4; ++rf) {
        const float* xp = x + (size_t)(rowbase + rf*16 + l15) * 64;
        #pragma unroll
        for (int kf = 0; kf < 2; ++kf) {
            const float* p = xp + kf*32 + kq*8;
            float4 v0 = ((const float4*)p)[0];
            float4 v1 = ((const float4*)p)[1];
            short8 a;
            a[0]=f2bf(v0.x); a[1]=f2bf(v0.y); a[2]=f2bf(v0.z); a[3]=f2bf(v0.w);
            a[4]=f2bf(v1.x); a[5]=f2bf(v1.y); a[6]=f2bf(v1.z); a[7]=f2bf(v1.w);
            afrag[rf][kf] = a;
        }
    }

    __syncthreads();

    // x2 values this lane needs: C/D layout col=lane&15, row=4*(lane>>4)+reg
    float xa[4][4];
    #pragma unroll
    for (int rf = 0; rf < 4; ++rf)
        #pragma unroll
        for (int r = 0; r < 4; ++r)
            xa[rf][r] = lds_x2[rf*16 + kq*4 + r];

    const float b   = bw[0];
    const float inv = -1.f / (2.f * b * b);
    const float q   = inv * 1.4426950408889634f;   // fold log2(e) -> exp2

    float s[4][4];
    #pragma unroll
    for (int rf = 0; rf < 4; ++rf)
        #pragma unroll
        for (int r = 0; r < 4; ++r) s[rf][r] = 0.f;

    const int span  = colend - colstart;
    const int niter = (span + 63) / 64;

    for (int it = 0; it < niter; ++it) {
        const int colb = colstart + it*64 + wave*16;
        const int col  = colb + l15;
        const int colc = min(col, N - 1);
        const bool valid = (col < colend);

        // B fragment: col = lane&15, k = 8*(lane>>4)+i ; load fp32, cvt->bf16
        const float* Xp = Xg + (size_t)colc * 64;
        const float* p0 = Xp + kq*8;
        const float* p1 = Xp + 32 + kq*8;
        float4 v0 = ((const float4*)p0)[0];
        float4 v1 = ((const float4*)p0)[1];
        float4 v2 = ((const float4*)p1)[0];
        float4 v3 = ((const float4*)p1)[1];

        // on-the-fly ||X_col||^2 (each lane holds 16 of the 64 elems)
        float pa = v0.x*v0.x + v0.y*v0.y + v0.z*v0.z + v0.w*v0.w
                 + v1.x*v1.x + v1.y*v1.y + v1.z*v1.z + v1.w*v1.w
                 + v2.x*v2.x + v2.y*v2.y + v2.z*v2.z + v2.w*v2.w
                 + v3.x*v3.x + v3.y*v3.y + v3.z*v3.z + v3.w*v3.w;
        pa += __shfl_xor(pa, 16);
        pa += __shfl_xor(pa, 32);   // full X2 for this lane's col

        short8 b0, b1;
        b0[0]=f2bf(v0.x); b0[1]=f2bf(v0.y); b0[2]=f2bf(v0.z); b0[3]=f2bf(v0.w);
        b0[4]=f2bf(v1.x); b0[5]=f2bf(v1.y); b0[6]=f2bf(v1.z); b0[7]=f2bf(v1.w);
        b1[0]=f2bf(v2.x); b1[1]=f2bf(v2.y); b1[2]=f2bf(v2.z); b1[3]=f2bf(v2.w);
        b1[4]=f2bf(v3.x); b1[5]=f2bf(v3.y); b1[6]=f2bf(v3.z); b1[7]=f2bf(v3.w);

        #pragma unroll
        for (int rf = 0; rf < 4; ++rf) {
            f32x4 acc = {0.f, 0.f, 0.f, 0.f};
            acc = __builtin_amdgcn_mfma_f32_16x16x32_bf16(afrag[rf][0], b0, acc, 0, 0, 0);
            acc = __builtin_amdgcn_mfma_f32_16x16x32_bf16(afrag[rf][1], b1, acc, 0, 0, 0);
            #pragma unroll
            for (int r = 0; r < 4; ++r) {
                float d2 = fmaf(-2.f, acc[r], xa[rf][r] + pa);
                d2 = fmaxf(d2, 0.f);
                float e = valid ? exp2f(d2 * q) : 0.f;
                s[rf][r] += e;
            }
        }
    }

    // ---- reduce across the 16 cols held by each 16-lane group ----
    #pragma unroll
    for (int rf = 0; rf < 4; ++rf)
        #pragma unroll
        for (int r = 0; r < 4; ++r) {
            float v = s[rf][r];
            v += __shfl_xor(v, 1);
            v += __shfl_xor(v, 2);
            v += __shfl_xor(v, 4);
            v += __shfl_xor(v, 8);
            s[rf][r] = v;
        }

    __syncthreads();
    if (l15 == 0) {
        #pragma unroll
        for (int rf = 0; rf < 4; ++rf)
            #pragma unroll
            for (int r = 0; r < 4; ++r)
                red[wave][rf*16 + kq*4 + r] = s[rf][r];
    }
    __syncthreads();

    if (tid < MTILE) {
        float tot = red[0][tid] + red[1][tid] + red[2][tid] + red[3][tid];
        if (nsplit == 1) {
            out[rowbase + tid] = logf(tot) + coeff;
        } else {
            ws[(size_t)split * M + rowbase + tid] = tot;
        }
    }
}

__global__ __launch_bounds__(256) void kde_combine(
    const float* __restrict__ ws, float* __restrict__ out,
    int M, int nsplit, float coeff)
{
    int i = blockIdx.x * 256 + threadIdx.x;
    if (i < M) {
        float t = 0.f;
        for (int s = 0; s < nsplit; ++s) t += ws[(size_t)s * M + i];
        out[i] = logf(t) + coeff;
    }
}

extern "C" void kernel_launch(void* const* d_in, const int* in_sizes, int n_in,
                              void* d_out, int out_size, void* d_ws, size_t ws_size,
                              hipStream_t stream) {
    const float* x  = (const float*)d_in[0];
    const float* Xg = (const float*)d_in[1];
    const float* bw = (const float*)d_in[2];
    float* out = (float*)d_out;

    const int M = in_sizes[0] / 64;
    const int N = in_sizes[1] / 64;
    // coeff = -log(n) - log(2*pi)*d/2 - log(BANDWIDTH_INIT)*d, d=64, BW_INIT=1
    const float coeff = -logf((float)N) - logf(2.f * (float)M_PI) * 32.f;

    int nsplit = NSPLIT;
    if (ws_size < (size_t)nsplit * M * sizeof(float)) nsplit = 1;

    dim3 grid(M / MTILE, nsplit);
    kde_main<<<grid, 256, 0, stream>>>(x, Xg, bw, (float*)d_ws, out, M, N, nsplit, coeff);
    if (nsplit > 1)
        kde_combine<<<(M + 255) / 256, 256, 0, stream>>>((const float*)d_ws, out, M, nsplit, coeff);
}

// Round 3
// 83.560 us; speedup vs baseline: 2.0986x; 2.0986x over previous
//
#include <hip/hip_runtime.h>
#include <hip/hip_bf16.h>
#include <math.h>

#define NSPLIT_NEW 32
#define NSPLIT_OLD 8

typedef __attribute__((ext_vector_type(8))) short short8;
typedef __attribute__((ext_vector_type(4))) float f32x4;

__device__ __forceinline__ short f2bf(float f) {
    __hip_bfloat16 h = __float2bfloat16(f);
    return __builtin_bit_cast(short, h);
}

// ---------------------------------------------------------------------------
// Preprocess: X -> bf16 (unscaled); x -> bf16 pre-scaled by (-2q).
// Store q*||row||^2 for both.  q = -log2(e)/(2 b^2), so
// acc = q*x2 + q*X2 + (-2q*x)·X = q*d2  and  exp2(q*d2) = exp(-d2/(2b^2)).
// ONLY the A side (x) carries the -2q scale — scaling both was the round-2 bug.
// 8 threads per row, 8 elems per thread (coalesced 32B reads / 16B writes).
// ---------------------------------------------------------------------------
__global__ __launch_bounds__(256) void kde_prep(
    const float* __restrict__ x, const float* __restrict__ Xg,
    const float* __restrict__ bw,
    short* __restrict__ Xb, float* __restrict__ X2q,
    short* __restrict__ xb, float* __restrict__ x2q, int M, int N)
{
    const int gid = blockIdx.x * 256 + threadIdx.x;
    const int row = gid >> 3;
    const int sub = gid & 7;
    const int total = M + N;
    if (row >= total) return;

    const float b = bw[0];
    const float q = -1.4426950408889634f / (2.f * b * b);
    const float s2q = -2.f * q;

    const float* src;
    short* dst;
    float* d2;
    float sc;
    if (row < N) {
        src = Xg + (size_t)row * 64; dst = Xb + (size_t)row * 64; d2 = X2q + row;
        sc = 1.f;                       // B operand: unscaled
    } else {
        int rm = row - N;
        src = x + (size_t)rm * 64; dst = xb + (size_t)rm * 64; d2 = x2q + rm;
        sc = s2q;                       // A operand: carries -2q
    }

    float4 v0 = ((const float4*)(src + sub * 8))[0];
    float4 v1 = ((const float4*)(src + sub * 8))[1];

    float ss = v0.x*v0.x + v0.y*v0.y + v0.z*v0.z + v0.w*v0.w
             + v1.x*v1.x + v1.y*v1.y + v1.z*v1.z + v1.w*v1.w;
    ss += __shfl_xor(ss, 1);
    ss += __shfl_xor(ss, 2);
    ss += __shfl_xor(ss, 4);

    short8 o;
    o[0]=f2bf(v0.x*sc); o[1]=f2bf(v0.y*sc); o[2]=f2bf(v0.z*sc); o[3]=f2bf(v0.w*sc);
    o[4]=f2bf(v1.x*sc); o[5]=f2bf(v1.y*sc); o[6]=f2bf(v1.z*sc); o[7]=f2bf(v1.w*sc);
    *(short8*)(dst + sub * 8) = o;

    if (sub == 0) *d2 = ss * q;
}

// ---------------------------------------------------------------------------
// Main: 64 x-rows per block, wave handles 32 cols/iter (2 groups of 16),
// block covers 128 cols/iter. MFMA acc initialized to q*(x2+X2) so the MFMA
// (A pre-scaled by -2q) emits logit = q*d2 directly.
// Epilogue per element: min(logit,0) -> exp2 -> accumulate.
// Masked cols get paq = -inf  =>  exp2(-inf) = 0.
// ---------------------------------------------------------------------------
__global__ __launch_bounds__(256, 3) void kde_main2(
    const short* __restrict__ Xb, const float* __restrict__ X2q,
    const short* __restrict__ xb, const float* __restrict__ x2q,
    float* __restrict__ partial, int M, int N, int chunk)
{
    const int tid  = threadIdx.x;
    const int lane = tid & 63;
    const int wave = tid >> 6;
    const int l15  = lane & 15;
    const int kq   = lane >> 4;
    const int rowbase  = blockIdx.x * 64;
    const int split    = blockIdx.y;
    const int colstart = split * chunk;
    const int colend   = min(colstart + chunk, N);
    const int niter    = max(0, (colend - colstart + 127) / 128);

    // A fragments (bf16, pre-scaled by -2q): row = lane&15, k = 8*(lane>>4)+i
    short8 afrag[4][2];
    #pragma unroll
    for (int rf = 0; rf < 4; ++rf) {
        const short* p = xb + (size_t)(rowbase + rf*16 + l15) * 64 + kq * 8;
        afrag[rf][0] = *(const short8*)(p);
        afrag[rf][1] = *(const short8*)(p + 32);
    }

    // q*||x||^2 for this lane's C/D rows: row = rf*16 + 4*kq + r
    f32x4 xaqv[4];
    #pragma unroll
    for (int rf = 0; rf < 4; ++rf)
        #pragma unroll
        for (int r = 0; r < 4; ++r)
            xaqv[rf][r] = x2q[rowbase + rf*16 + kq*4 + r];

    float s[2][4][4];
    #pragma unroll
    for (int g = 0; g < 2; ++g)
        #pragma unroll
        for (int rf = 0; rf < 4; ++rf)
            #pragma unroll
            for (int r = 0; r < 4; ++r) s[g][rf][r] = 0.f;

    auto LOADB = [&](short8 B[2][2], float* paq, int it) {
        #pragma unroll
        for (int g = 0; g < 2; ++g) {
            const int col  = colstart + it*128 + wave*32 + g*16 + l15;
            const int colc = min(col, N - 1);
            const short* p = Xb + (size_t)colc * 64 + kq * 8;
            B[g][0] = *(const short8*)(p);
            B[g][1] = *(const short8*)(p + 32);
            paq[g] = (col < colend) ? X2q[colc] : -INFINITY;
        }
    };

    auto COMPUTE = [&](short8 B[2][2], const float* paq) {
        #pragma unroll
        for (int g = 0; g < 2; ++g) {
            #pragma unroll
            for (int rf = 0; rf < 4; ++rf) {
                f32x4 acc;
                #pragma unroll
                for (int r = 0; r < 4; ++r) acc[r] = xaqv[rf][r] + paq[g];
                acc = __builtin_amdgcn_mfma_f32_16x16x32_bf16(afrag[rf][0], B[g][0], acc, 0, 0, 0);
                acc = __builtin_amdgcn_mfma_f32_16x16x32_bf16(afrag[rf][1], B[g][1], acc, 0, 0, 0);
                #pragma unroll
                for (int r = 0; r < 4; ++r)
                    s[g][rf][r] += __builtin_amdgcn_exp2f(fminf(acc[r], 0.f));
            }
        }
    };

    // double-buffered prefetch, named buffers (no runtime-indexed arrays)
    short8 b0[2][2], b1[2][2];
    float p0[2], p1[2];
    if (niter > 0) LOADB(b0, p0, 0);
    for (int it = 0; it < niter; it += 2) {
        if (it + 1 < niter) LOADB(b1, p1, it + 1);
        COMPUTE(b0, p0);
        if (it + 1 < niter) {
            if (it + 2 < niter) LOADB(b0, p0, it + 2);
            COMPUTE(b1, p1);
        }
    }

    // reduce: combine groups, then across the 16 lanes holding cols
    float t[4][4];
    #pragma unroll
    for (int rf = 0; rf < 4; ++rf)
        #pragma unroll
        for (int r = 0; r < 4; ++r) {
            float v = s[0][rf][r] + s[1][rf][r];
            v += __shfl_xor(v, 1);
            v += __shfl_xor(v, 2);
            v += __shfl_xor(v, 4);
            v += __shfl_xor(v, 8);
            t[rf][r] = v;
        }

    __shared__ float red[4][64];
    if (l15 == 0) {
        #pragma unroll
        for (int rf = 0; rf < 4; ++rf)
            #pragma unroll
            for (int r = 0; r < 4; ++r)
                red[wave][rf*16 + kq*4 + r] = t[rf][r];
    }
    __syncthreads();
    if (tid < 64) {
        partial[(size_t)split * M + rowbase + tid] =
            red[0][tid] + red[1][tid] + red[2][tid] + red[3][tid];
    }
}

__global__ __launch_bounds__(256) void kde_combine(
    const float* __restrict__ ws, float* __restrict__ out,
    int M, int nsplit, float coeff)
{
    int i = blockIdx.x * 256 + threadIdx.x;
    if (i < M) {
        float t = 0.f;
        for (int s = 0; s < nsplit; ++s) t += ws[(size_t)s * M + i];
        out[i] = logf(t) + coeff;
    }
}

// ---------------------------------------------------------------------------
// Fallback (round-1) kernel: fused fp32-load path, used only if ws too small.
// ---------------------------------------------------------------------------
__global__ __launch_bounds__(256) void kde_main_fb(
    const float* __restrict__ x, const float* __restrict__ Xg,
    const float* __restrict__ bw, float* __restrict__ ws,
    float* __restrict__ out, int M, int N, int nsplit, float coeff)
{
    const int tid  = threadIdx.x;
    const int lane = tid & 63;
    const int wave = tid >> 6;
    const int l15  = lane & 15;
    const int kq   = lane >> 4;
    const int rowbase = blockIdx.x * 64;
    const int split   = blockIdx.y;
    const int chunk   = (N + nsplit - 1) / nsplit;
    const int colstart = split * chunk;
    const int colend   = min(colstart + chunk, N);

    __shared__ float lds_x2[64];
    __shared__ float red[4][64];

    if (tid < 64) {
        const float* xp = x + (size_t)(rowbase + tid) * 64;
        float ssum = 0.f;
        #pragma unroll
        for (int k = 0; k < 16; ++k) {
            float4 v = ((const float4*)xp)[k];
            ssum += v.x*v.x + v.y*v.y + v.z*v.z + v.w*v.w;
        }
        lds_x2[tid] = ssum;
    }

    short8 afrag[4][2];
    #pragma unroll
    for (int rf = 0; rf < 4; ++rf) {
        const float* xp = x + (size_t)(rowbase + rf*16 + l15) * 64;
        #pragma unroll
        for (int kf = 0; kf < 2; ++kf) {
            const float* p = xp + kf*32 + kq*8;
            float4 v0 = ((const float4*)p)[0];
            float4 v1 = ((const float4*)p)[1];
            short8 a;
            a[0]=f2bf(v0.x); a[1]=f2bf(v0.y); a[2]=f2bf(v0.z); a[3]=f2bf(v0.w);
            a[4]=f2bf(v1.x); a[5]=f2bf(v1.y); a[6]=f2bf(v1.z); a[7]=f2bf(v1.w);
            afrag[rf][kf] = a;
        }
    }
    __syncthreads();

    float xa[4][4];
    #pragma unroll
    for (int rf = 0; rf < 4; ++rf)
        #pragma unroll
        for (int r = 0; r < 4; ++r)
            xa[rf][r] = lds_x2[rf*16 + kq*4 + r];

    const float b   = bw[0];
    const float q   = -1.4426950408889634f / (2.f * b * b);

    float s[4][4];
    #pragma unroll
    for (int rf = 0; rf < 4; ++rf)
        #pragma unroll
        for (int r = 0; r < 4; ++r) s[rf][r] = 0.f;

    const int span  = colend - colstart;
    const int niter = (span + 63) / 64;

    for (int it = 0; it < niter; ++it) {
        const int col  = colstart + it*64 + wave*16 + l15;
        const int colc = min(col, N - 1);
        const bool valid = (col < colend);

        const float* Xp = Xg + (size_t)colc * 64;
        float4 v0 = ((const float4*)(Xp + kq*8))[0];
        float4 v1 = ((const float4*)(Xp + kq*8))[1];
        float4 v2 = ((const float4*)(Xp + 32 + kq*8))[0];
        float4 v3 = ((const float4*)(Xp + 32 + kq*8))[1];

        float pa = v0.x*v0.x + v0.y*v0.y + v0.z*v0.z + v0.w*v0.w
                 + v1.x*v1.x + v1.y*v1.y + v1.z*v1.z + v1.w*v1.w
                 + v2.x*v2.x + v2.y*v2.y + v2.z*v2.z + v2.w*v2.w
                 + v3.x*v3.x + v3.y*v3.y + v3.z*v3.z + v3.w*v3.w;
        pa += __shfl_xor(pa, 16);
        pa += __shfl_xor(pa, 32);

        short8 bb0, bb1;
        bb0[0]=f2bf(v0.x); bb0[1]=f2bf(v0.y); bb0[2]=f2bf(v0.z); bb0[3]=f2bf(v0.w);
        bb0[4]=f2bf(v1.x); bb0[5]=f2bf(v1.y); bb0[6]=f2bf(v1.z); bb0[7]=f2bf(v1.w);
        bb1[0]=f2bf(v2.x); bb1[1]=f2bf(v2.y); bb1[2]=f2bf(v2.z); bb1[3]=f2bf(v2.w);
        bb1[4]=f2bf(v3.x); bb1[5]=f2bf(v3.y); bb1[6]=f2bf(v3.z); bb1[7]=f2bf(v3.w);

        #pragma unroll
        for (int rf = 0; rf < 4; ++rf) {
            f32x4 acc = {0.f, 0.f, 0.f, 0.f};
            acc = __builtin_amdgcn_mfma_f32_16x16x32_bf16(afrag[rf][0], bb0, acc, 0, 0, 0);
            acc = __builtin_amdgcn_mfma_f32_16x16x32_bf16(afrag[rf][1], bb1, acc, 0, 0, 0);
            #pragma unroll
            for (int r = 0; r < 4; ++r) {
                float d2 = fmaxf(xa[rf][r] + pa - 2.f*acc[r], 0.f);
                float e = valid ? __builtin_amdgcn_exp2f(d2 * q) : 0.f;
                s[rf][r] += e;
            }
        }
    }

    #pragma unroll
    for (int rf = 0; rf < 4; ++rf)
        #pragma unroll
        for (int r = 0; r < 4; ++r) {
            float v = s[rf][r];
            v += __shfl_xor(v, 1);
            v += __shfl_xor(v, 2);
            v += __shfl_xor(v, 4);
            v += __shfl_xor(v, 8);
            s[rf][r] = v;
        }

    __syncthreads();
    if (l15 == 0) {
        #pragma unroll
        for (int rf = 0; rf < 4; ++rf)
            #pragma unroll
            for (int r = 0; r < 4; ++r)
                red[wave][rf*16 + kq*4 + r] = s[rf][r];
    }
    __syncthreads();

    if (tid < 64) {
        float tot = red[0][tid] + red[1][tid] + red[2][tid] + red[3][tid];
        if (nsplit == 1) out[rowbase + tid] = logf(tot) + coeff;
        else             ws[(size_t)split * M + rowbase + tid] = tot;
    }
}

extern "C" void kernel_launch(void* const* d_in, const int* in_sizes, int n_in,
                              void* d_out, int out_size, void* d_ws, size_t ws_size,
                              hipStream_t stream) {
    const float* x  = (const float*)d_in[0];
    const float* Xg = (const float*)d_in[1];
    const float* bw = (const float*)d_in[2];
    float* out = (float*)d_out;

    const int M = in_sizes[0] / 64;
    const int N = in_sizes[1] / 64;
    const float coeff = -logf((float)N) - logf(2.f * (float)M_PI) * 32.f;

    // workspace layout (256B-aligned chunks)
    auto align256 = [](size_t v) { return (v + 255) & ~(size_t)255; };
    const size_t szXb   = align256((size_t)N * 64 * sizeof(short));
    const size_t szxb   = align256((size_t)M * 64 * sizeof(short));
    const size_t szX2q  = align256((size_t)N * sizeof(float));
    const size_t szx2q  = align256((size_t)M * sizeof(float));
    const size_t szPart = align256((size_t)NSPLIT_NEW * M * sizeof(float));
    const size_t need   = szXb + szxb + szX2q + szx2q + szPart;

    if (ws_size >= need) {
        char* w = (char*)d_ws;
        short* Xb   = (short*)(w);
        short* xb   = (short*)(w + szXb);
        float* X2q  = (float*)(w + szXb + szxb);
        float* x2q  = (float*)(w + szXb + szxb + szX2q);
        float* part = (float*)(w + szXb + szxb + szX2q + szx2q);

        const int totalRows = M + N;
        kde_prep<<<(totalRows * 8 + 255) / 256, 256, 0, stream>>>(
            x, Xg, bw, Xb, X2q, xb, x2q, M, N);

        const int chunk = (((N + NSPLIT_NEW - 1) / NSPLIT_NEW) + 127) & ~127;
        dim3 grid(M / 64, NSPLIT_NEW);
        kde_main2<<<grid, 256, 0, stream>>>(Xb, X2q, xb, x2q, part, M, N, chunk);

        kde_combine<<<(M + 255) / 256, 256, 0, stream>>>(part, out, M, NSPLIT_NEW, coeff);
    } else {
        int nsplit = NSPLIT_OLD;
        if (ws_size < (size_t)nsplit * M * sizeof(float)) nsplit = 1;
        dim3 grid(M / 64, nsplit);
        kde_main_fb<<<grid, 256, 0, stream>>>(x, Xg, bw, (float*)d_ws, out, M, N, nsplit, coeff);
        if (nsplit > 1)
            kde_combine<<<(M + 255) / 256, 256, 0, stream>>>((const float*)d_ws, out, M, nsplit, coeff);
    }
}

// Round 4
// 80.468 us; speedup vs baseline: 2.1792x; 1.0384x over previous
//
#include <hip/hip_runtime.h>
#include <hip/hip_bf16.h>
#include <math.h>

#define NSPLIT_NEW 32
#define NSPLIT_OLD 8

typedef __attribute__((ext_vector_type(8))) short short8;
typedef __attribute__((ext_vector_type(4))) float f32x4;

__device__ __forceinline__ short f2bf(float f) {
    __hip_bfloat16 h = __float2bfloat16(f);
    return __builtin_bit_cast(short, h);
}

// ---------------------------------------------------------------------------
// Preprocess:
//   X rows -> Xb bf16 (unscaled)  + Eq[col] = exp2(q*||X||^2)  (f32)
//   x rows -> xb bf16 scaled by -2q + x2q[row] = q*||x||^2     (f32)
// q = -log2(e)/(2 b^2).  Then  exp(-d2/(2b^2)) = exp2(q*d2)
//   = exp2(q*x2) * Eq[col] * exp2((-2q*x)·X)
// Row factor exp2(q*x2) is applied in log-space in the combine kernel.
// ---------------------------------------------------------------------------
__global__ __launch_bounds__(256) void kde_prep(
    const float* __restrict__ x, const float* __restrict__ Xg,
    const float* __restrict__ bw,
    short* __restrict__ Xb, float* __restrict__ Eq,
    short* __restrict__ xb, float* __restrict__ x2q, int M, int N)
{
    const int gid = blockIdx.x * 256 + threadIdx.x;
    const int row = gid >> 3;
    const int sub = gid & 7;
    const int total = M + N;
    if (row >= total) return;

    const float b = bw[0];
    const float q = -1.4426950408889634f / (2.f * b * b);
    const float s2q = -2.f * q;

    const float* src;
    short* dst;
    float sc;
    if (row < N) { src = Xg + (size_t)row * 64;       dst = Xb + (size_t)row * 64;       sc = 1.f; }
    else         { src = x  + (size_t)(row-N) * 64;   dst = xb + (size_t)(row-N) * 64;   sc = s2q; }

    float4 v0 = ((const float4*)(src + sub * 8))[0];
    float4 v1 = ((const float4*)(src + sub * 8))[1];

    float ss = v0.x*v0.x + v0.y*v0.y + v0.z*v0.z + v0.w*v0.w
             + v1.x*v1.x + v1.y*v1.y + v1.z*v1.z + v1.w*v1.w;
    ss += __shfl_xor(ss, 1);
    ss += __shfl_xor(ss, 2);
    ss += __shfl_xor(ss, 4);

    short8 o;
    o[0]=f2bf(v0.x*sc); o[1]=f2bf(v0.y*sc); o[2]=f2bf(v0.z*sc); o[3]=f2bf(v0.w*sc);
    o[4]=f2bf(v1.x*sc); o[5]=f2bf(v1.y*sc); o[6]=f2bf(v1.z*sc); o[7]=f2bf(v1.w*sc);
    *(short8*)(dst + sub * 8) = o;

    if (sub == 0) {
        if (row < N) Eq[row] = exp2f(ss * q);
        else         x2q[row - N] = ss * q;
    }
}

// ---------------------------------------------------------------------------
// Main: 64 x-rows per block, wave handles 32 cols/iter (2 groups of 16).
// acc = MFMA(cross) with a loop-invariant ZERO C tuple (no per-element init);
// epilogue per element: exp2 + fma with the per-column factor Eq.
// Full iterations are unmasked; a single masked tail handles the remainder.
// ---------------------------------------------------------------------------
__global__ __launch_bounds__(256) void kde_main3(
    const short* __restrict__ Xb, const float* __restrict__ Eq,
    const short* __restrict__ xb,
    float* __restrict__ partial, int M, int N, int chunk)
{
    const int tid  = threadIdx.x;
    const int lane = tid & 63;
    const int wave = tid >> 6;
    const int l15  = lane & 15;
    const int kq   = lane >> 4;
    const int rowbase  = blockIdx.x * 64;
    const int split    = blockIdx.y;
    const int colstart = split * chunk;
    const int colend   = min(colstart + chunk, N);
    const int span     = max(0, colend - colstart);
    const int nfull    = span >> 7;          // complete 128-col iterations
    const int rem      = span & 127;

    // A fragments (bf16, pre-scaled by -2q): row = lane&15, k = 8*(lane>>4)+i
    short8 afrag[4][2];
    #pragma unroll
    for (int rf = 0; rf < 4; ++rf) {
        const short* p = xb + (size_t)(rowbase + rf*16 + l15) * 64 + kq * 8;
        afrag[rf][0] = *(const short8*)(p);
        afrag[rf][1] = *(const short8*)(p + 32);
    }

    const f32x4 zero4 = {0.f, 0.f, 0.f, 0.f};

    float s[2][4][4];
    #pragma unroll
    for (int g = 0; g < 2; ++g)
        #pragma unroll
        for (int rf = 0; rf < 4; ++rf)
            #pragma unroll
            for (int r = 0; r < 4; ++r) s[g][rf][r] = 0.f;

    auto LOADB = [&](short8 B[2][2], float* E, int it) {
        #pragma unroll
        for (int g = 0; g < 2; ++g) {
            const int col  = colstart + it*128 + wave*32 + g*16 + l15;
            const short* p = Xb + (size_t)col * 64 + kq * 8;
            B[g][0] = *(const short8*)(p);
            B[g][1] = *(const short8*)(p + 32);
            E[g] = Eq[col];
        }
    };

    auto COMPUTE = [&](short8 B[2][2], const float* E) {
        #pragma unroll
        for (int g = 0; g < 2; ++g) {
            #pragma unroll
            for (int rf = 0; rf < 4; ++rf) {
                f32x4 acc = __builtin_amdgcn_mfma_f32_16x16x32_bf16(afrag[rf][0], B[g][0], zero4, 0, 0, 0);
                acc = __builtin_amdgcn_mfma_f32_16x16x32_bf16(afrag[rf][1], B[g][1], acc, 0, 0, 0);
                #pragma unroll
                for (int r = 0; r < 4; ++r)
                    s[g][rf][r] = fmaf(E[g], __builtin_amdgcn_exp2f(acc[r]), s[g][rf][r]);
            }
        }
    };

    // double-buffered prefetch over full (unmasked) iterations
    short8 b0[2][2], b1[2][2];
    float e0[2], e1[2];
    if (nfull > 0) LOADB(b0, e0, 0);
    for (int it = 0; it < nfull; it += 2) {
        if (it + 1 < nfull) LOADB(b1, e1, it + 1);
        COMPUTE(b0, e0);
        if (it + 1 < nfull) {
            if (it + 2 < nfull) LOADB(b0, e0, it + 2);
            COMPUTE(b1, e1);
        }
    }

    // masked tail (at most one iteration)
    if (rem) {
        #pragma unroll
        for (int g = 0; g < 2; ++g) {
            const int col  = colstart + nfull*128 + wave*32 + g*16 + l15;
            const int colc = min(col, N - 1);
            const short* p = Xb + (size_t)colc * 64 + kq * 8;
            b0[g][0] = *(const short8*)(p);
            b0[g][1] = *(const short8*)(p + 32);
            e0[g] = (col < colend) ? Eq[colc] : 0.f;
        }
        COMPUTE(b0, e0);
    }

    // reduce: combine groups, then across the 16 lanes holding cols
    float t[4][4];
    #pragma unroll
    for (int rf = 0; rf < 4; ++rf)
        #pragma unroll
        for (int r = 0; r < 4; ++r) {
            float v = s[0][rf][r] + s[1][rf][r];
            v += __shfl_xor(v, 1);
            v += __shfl_xor(v, 2);
            v += __shfl_xor(v, 4);
            v += __shfl_xor(v, 8);
            t[rf][r] = v;
        }

    __shared__ float red[4][64];
    if (l15 == 0) {
        #pragma unroll
        for (int rf = 0; rf < 4; ++rf)
            #pragma unroll
            for (int r = 0; r < 4; ++r)
                red[wave][rf*16 + kq*4 + r] = t[rf][r];
    }
    __syncthreads();
    if (tid < 64) {
        partial[(size_t)split * M + rowbase + tid] =
            red[0][tid] + red[1][tid] + red[2][tid] + red[3][tid];
    }
}

__global__ __launch_bounds__(256) void kde_combine2(
    const float* __restrict__ ws, const float* __restrict__ x2q,
    float* __restrict__ out, int M, int nsplit, float coeff)
{
    int i = blockIdx.x * 256 + threadIdx.x;
    if (i < M) {
        float t = 0.f;
        for (int s = 0; s < nsplit; ++s) t += ws[(size_t)s * M + i];
        // out = ln2 * (q*||x||^2) + log(sum) + coeff
        out[i] = fmaf(0.6931471805599453f, x2q[i], logf(t) + coeff);
    }
}

// ---------------------------------------------------------------------------
// Fallback (round-1 style) fused fp32 path: used only if ws too small.
// ---------------------------------------------------------------------------
__global__ __launch_bounds__(256) void kde_main_fb(
    const float* __restrict__ x, const float* __restrict__ Xg,
    const float* __restrict__ bw, float* __restrict__ ws,
    float* __restrict__ out, int M, int N, int nsplit, float coeff)
{
    const int tid  = threadIdx.x;
    const int lane = tid & 63;
    const int wave = tid >> 6;
    const int l15  = lane & 15;
    const int kq   = lane >> 4;
    const int rowbase = blockIdx.x * 64;
    const int split   = blockIdx.y;
    const int chunk   = (N + nsplit - 1) / nsplit;
    const int colstart = split * chunk;
    const int colend   = min(colstart + chunk, N);

    __shared__ float lds_x2[64];
    __shared__ float red[4][64];

    if (tid < 64) {
        const float* xp = x + (size_t)(rowbase + tid) * 64;
        float ssum = 0.f;
        #pragma unroll
        for (int k = 0; k < 16; ++k) {
            float4 v = ((const float4*)xp)[k];
            ssum += v.x*v.x + v.y*v.y + v.z*v.z + v.w*v.w;
        }
        lds_x2[tid] = ssum;
    }

    short8 afrag[4][2];
    #pragma unroll
    for (int rf = 0; rf < 4; ++rf) {
        const float* xp = x + (size_t)(rowbase + rf*16 + l15) * 64;
        #pragma unroll
        for (int kf = 0; kf < 2; ++kf) {
            const float* p = xp + kf*32 + kq*8;
            float4 v0 = ((const float4*)p)[0];
            float4 v1 = ((const float4*)p)[1];
            short8 a;
            a[0]=f2bf(v0.x); a[1]=f2bf(v0.y); a[2]=f2bf(v0.z); a[3]=f2bf(v0.w);
            a[4]=f2bf(v1.x); a[5]=f2bf(v1.y); a[6]=f2bf(v1.z); a[7]=f2bf(v1.w);
            afrag[rf][kf] = a;
        }
    }
    __syncthreads();

    float xa[4][4];
    #pragma unroll
    for (int rf = 0; rf < 4; ++rf)
        #pragma unroll
        for (int r = 0; r < 4; ++r)
            xa[rf][r] = lds_x2[rf*16 + kq*4 + r];

    const float b = bw[0];
    const float q = -1.4426950408889634f / (2.f * b * b);

    float s[4][4];
    #pragma unroll
    for (int rf = 0; rf < 4; ++rf)
        #pragma unroll
        for (int r = 0; r < 4; ++r) s[rf][r] = 0.f;

    const int span  = colend - colstart;
    const int niter = (span + 63) / 64;

    for (int it = 0; it < niter; ++it) {
        const int col  = colstart + it*64 + wave*16 + l15;
        const int colc = min(col, N - 1);
        const bool valid = (col < colend);

        const float* Xp = Xg + (size_t)colc * 64;
        float4 v0 = ((const float4*)(Xp + kq*8))[0];
        float4 v1 = ((const float4*)(Xp + kq*8))[1];
        float4 v2 = ((const float4*)(Xp + 32 + kq*8))[0];
        float4 v3 = ((const float4*)(Xp + 32 + kq*8))[1];

        float pa = v0.x*v0.x + v0.y*v0.y + v0.z*v0.z + v0.w*v0.w
                 + v1.x*v1.x + v1.y*v1.y + v1.z*v1.z + v1.w*v1.w
                 + v2.x*v2.x + v2.y*v2.y + v2.z*v2.z + v2.w*v2.w
                 + v3.x*v3.x + v3.y*v3.y + v3.z*v3.z + v3.w*v3.w;
        pa += __shfl_xor(pa, 16);
        pa += __shfl_xor(pa, 32);

        short8 bb0, bb1;
        bb0[0]=f2bf(v0.x); bb0[1]=f2bf(v0.y); bb0[2]=f2bf(v0.z); bb0[3]=f2bf(v0.w);
        bb0[4]=f2bf(v1.x); bb0[5]=f2bf(v1.y); bb0[6]=f2bf(v1.z); bb0[7]=f2bf(v1.w);
        bb1[0]=f2bf(v2.x); bb1[1]=f2bf(v2.y); bb1[2]=f2bf(v2.z); bb1[3]=f2bf(v2.w);
        bb1[4]=f2bf(v3.x); bb1[5]=f2bf(v3.y); bb1[6]=f2bf(v3.z); bb1[7]=f2bf(v3.w);

        #pragma unroll
        for (int rf = 0; rf < 4; ++rf) {
            f32x4 acc = {0.f, 0.f, 0.f, 0.f};
            acc = __builtin_amdgcn_mfma_f32_16x16x32_bf16(afrag[rf][0], bb0, acc, 0, 0, 0);
            acc = __builtin_amdgcn_mfma_f32_16x16x32_bf16(afrag[rf][1], bb1, acc, 0, 0, 0);
            #pragma unroll
            for (int r = 0; r < 4; ++r) {
                float d2 = fmaxf(xa[rf][r] + pa - 2.f*acc[r], 0.f);
                float e = valid ? __builtin_amdgcn_exp2f(d2 * q) : 0.f;
                s[rf][r] += e;
            }
        }
    }

    #pragma unroll
    for (int rf = 0; rf < 4; ++rf)
        #pragma unroll
        for (int r = 0; r < 4; ++r) {
            float v = s[rf][r];
            v += __shfl_xor(v, 1);
            v += __shfl_xor(v, 2);
            v += __shfl_xor(v, 4);
            v += __shfl_xor(v, 8);
            s[rf][r] = v;
        }

    __syncthreads();
    if (l15 == 0) {
        #pragma unroll
        for (int rf = 0; rf < 4; ++rf)
            #pragma unroll
            for (int r = 0; r < 4; ++r)
                red[wave][rf*16 + kq*4 + r] = s[rf][r];
    }
    __syncthreads();

    if (tid < 64) {
        float tot = red[0][tid] + red[1][tid] + red[2][tid] + red[3][tid];
        if (nsplit == 1) out[rowbase + tid] = logf(tot) + coeff;
        else             ws[(size_t)split * M + rowbase + tid] = tot;
    }
}

__global__ __launch_bounds__(256) void kde_combine_fb(
    const float* __restrict__ ws, float* __restrict__ out,
    int M, int nsplit, float coeff)
{
    int i = blockIdx.x * 256 + threadIdx.x;
    if (i < M) {
        float t = 0.f;
        for (int s = 0; s < nsplit; ++s) t += ws[(size_t)s * M + i];
        out[i] = logf(t) + coeff;
    }
}

extern "C" void kernel_launch(void* const* d_in, const int* in_sizes, int n_in,
                              void* d_out, int out_size, void* d_ws, size_t ws_size,
                              hipStream_t stream) {
    const float* x  = (const float*)d_in[0];
    const float* Xg = (const float*)d_in[1];
    const float* bw = (const float*)d_in[2];
    float* out = (float*)d_out;

    const int M = in_sizes[0] / 64;
    const int N = in_sizes[1] / 64;
    const float coeff = -logf((float)N) - logf(2.f * (float)M_PI) * 32.f;

    auto align256 = [](size_t v) { return (v + 255) & ~(size_t)255; };
    const size_t szXb   = align256((size_t)N * 64 * sizeof(short));
    const size_t szxb   = align256((size_t)M * 64 * sizeof(short));
    const size_t szEq   = align256((size_t)N * sizeof(float));
    const size_t szx2q  = align256((size_t)M * sizeof(float));
    const size_t szPart = align256((size_t)NSPLIT_NEW * M * sizeof(float));
    const size_t need   = szXb + szxb + szEq + szx2q + szPart;

    if (ws_size >= need) {
        char* w = (char*)d_ws;
        short* Xb   = (short*)(w);
        short* xb   = (short*)(w + szXb);
        float* Eq   = (float*)(w + szXb + szxb);
        float* x2q  = (float*)(w + szXb + szxb + szEq);
        float* part = (float*)(w + szXb + szxb + szEq + szx2q);

        const int totalRows = M + N;
        kde_prep<<<(totalRows * 8 + 255) / 256, 256, 0, stream>>>(
            x, Xg, bw, Xb, Eq, xb, x2q, M, N);

        const int chunk = (((N + NSPLIT_NEW - 1) / NSPLIT_NEW) + 127) & ~127;
        dim3 grid(M / 64, NSPLIT_NEW);
        kde_main3<<<grid, 256, 0, stream>>>(Xb, Eq, xb, part, M, N, chunk);

        kde_combine2<<<(M + 255) / 256, 256, 0, stream>>>(part, x2q, out, M, NSPLIT_NEW, coeff);
    } else {
        int nsplit = NSPLIT_OLD;
        if (ws_size < (size_t)nsplit * M * sizeof(float)) nsplit = 1;
        dim3 grid(M / 64, nsplit);
        kde_main_fb<<<grid, 256, 0, stream>>>(x, Xg, bw, (float*)d_ws, out, M, N, nsplit, coeff);
        if (nsplit > 1)
            kde_combine_fb<<<(M + 255) / 256, 256, 0, stream>>>((const float*)d_ws, out, M, nsplit, coeff);
    }
}

// Round 5
// 77.400 us; speedup vs baseline: 2.2656x; 1.0396x over previous
//
#include <hip/hip_runtime.h>
#include <hip/hip_bf16.h>
#include <math.h>

#define NSPLIT 32

typedef __attribute__((ext_vector_type(8))) short short8;
typedef __attribute__((ext_vector_type(4))) float f32x4;

__device__ __forceinline__ short f2bf(float f) {
    __hip_bfloat16 h = __float2bfloat16(f);
    return __builtin_bit_cast(short, h);
}

// ---------------------------------------------------------------------------
// Preprocess:
//   X rows -> Xb bf16 (unscaled)  + Eq[col] = exp2(q*||X||^2)  (f32)
//   x rows -> xb bf16 scaled by -2q + x2q[row] = q*||x||^2     (f32)
// q = -log2(e)/(2 b^2).  exp(-d2/(2b^2)) = exp2(q*x2) * Eq[col] * exp2((-2q x)·X)
// Row factor exp2(q*x2) applied in log-space in the combine kernel.
// ---------------------------------------------------------------------------
__global__ __launch_bounds__(256) void kde_prep(
    const float* __restrict__ x, const float* __restrict__ Xg,
    const float* __restrict__ bw,
    short* __restrict__ Xb, float* __restrict__ Eq,
    short* __restrict__ xb, float* __restrict__ x2q, int M, int N)
{
    const int gid = blockIdx.x * 256 + threadIdx.x;
    const int row = gid >> 3;
    const int sub = gid & 7;
    if (row >= M + N) return;

    const float b = bw[0];
    const float q = -1.4426950408889634f / (2.f * b * b);
    const float s2q = -2.f * q;

    const float* src;
    short* dst;
    float sc;
    if (row < N) { src = Xg + (size_t)row * 64;     dst = Xb + (size_t)row * 64;     sc = 1.f; }
    else         { src = x  + (size_t)(row-N) * 64; dst = xb + (size_t)(row-N) * 64; sc = s2q; }

    float4 v0 = ((const float4*)(src + sub * 8))[0];
    float4 v1 = ((const float4*)(src + sub * 8))[1];

    float ss = v0.x*v0.x + v0.y*v0.y + v0.z*v0.z + v0.w*v0.w
             + v1.x*v1.x + v1.y*v1.y + v1.z*v1.z + v1.w*v1.w;
    ss += __shfl_xor(ss, 1);
    ss += __shfl_xor(ss, 2);
    ss += __shfl_xor(ss, 4);

    short8 o;
    o[0]=f2bf(v0.x*sc); o[1]=f2bf(v0.y*sc); o[2]=f2bf(v0.z*sc); o[3]=f2bf(v0.w*sc);
    o[4]=f2bf(v1.x*sc); o[5]=f2bf(v1.y*sc); o[6]=f2bf(v1.z*sc); o[7]=f2bf(v1.w*sc);
    *(short8*)(dst + sub * 8) = o;

    if (sub == 0) {
        if (row < N) Eq[row] = exp2f(ss * q);
        else         x2q[row - N] = ss * q;
    }
}

// ---------------------------------------------------------------------------
// Main: 64 x-rows per block, 4 waves; each wave owns 32 cols/iter (2 g-groups
// of 16), block covers 128 cols/iter. Work split in whole 128-col iteration
// units across NSPLIT splits; only the single global-last iteration is masked.
//
// Per iteration, phase-split pipeline:
//   LOAD(k+1)  ->  MFMA-phase(k): 16 MFMAs into 8 named f32x4 accs
//              ->  EXP-phase(k): 32 exp2 + 32 fma (accs fully drained by now)
// ---------------------------------------------------------------------------
__global__ __launch_bounds__(256, 4) void kde_main4(
    const short* __restrict__ Xb, const float* __restrict__ Eq,
    const short* __restrict__ xb,
    float* __restrict__ partial, int M, int N)
{
    const int tid  = threadIdx.x;
    const int lane = tid & 63;
    const int wave = tid >> 6;
    const int l15  = lane & 15;
    const int kq   = lane >> 4;
    const int rowbase = blockIdx.x * 64;
    const int split   = blockIdx.y;

    const int T    = (N + 127) >> 7;          // total 128-col iterations
    const int base = T / NSPLIT;
    const int remu = T % NSPLIT;
    const int it0  = split * base + min(split, remu);
    const int cnt  = base + (split < remu ? 1 : 0);
    const bool maskedLast = (it0 + cnt == T) && ((N & 127) != 0);
    const int nfull = cnt - (maskedLast ? 1 : 0);

    // A fragments (bf16, pre-scaled by -2q): row = lane&15, k = 8*(lane>>4)+i
    short8 afrag[4][2];
    #pragma unroll
    for (int rf = 0; rf < 4; ++rf) {
        const short* p = xb + (size_t)(rowbase + rf*16 + l15) * 64 + kq * 8;
        afrag[rf][0] = *(const short8*)(p);
        afrag[rf][1] = *(const short8*)(p + 32);
    }

    const f32x4 zero4 = {0.f, 0.f, 0.f, 0.f};

    float s[4][4];
    #pragma unroll
    for (int rf = 0; rf < 4; ++rf)
        #pragma unroll
        for (int r = 0; r < 4; ++r) s[rf][r] = 0.f;

    // streaming pointers (per-iter stride: 128 cols)
    const short* pB0 = Xb + (size_t)(it0*128 + wave*32 + l15) * 64 + kq * 8;
    const short* pB1 = pB0 + 16 * 64;
    const float* pE0 = Eq + it0*128 + wave*32 + l15;
    const float* pE1 = pE0 + 16;
    const size_t strideB = (size_t)128 * 64;

    f32x4 acc0[4], acc1[4];

    auto LOAD = [&](short8& B00, short8& B01, short8& B10, short8& B11,
                    float& E0, float& E1) {
        B00 = *(const short8*)(pB0);
        B01 = *(const short8*)(pB0 + 32);
        B10 = *(const short8*)(pB1);
        B11 = *(const short8*)(pB1 + 32);
        E0 = *pE0; E1 = *pE1;
        pB0 += strideB; pB1 += strideB; pE0 += 128; pE1 += 128;
    };

    auto MFMAPH = [&](short8 B00, short8 B01, short8 B10, short8 B11) {
        #pragma unroll
        for (int rf = 0; rf < 4; ++rf) {
            f32x4 a = __builtin_amdgcn_mfma_f32_16x16x32_bf16(afrag[rf][0], B00, zero4, 0, 0, 0);
            acc0[rf] = __builtin_amdgcn_mfma_f32_16x16x32_bf16(afrag[rf][1], B01, a, 0, 0, 0);
        }
        #pragma unroll
        for (int rf = 0; rf < 4; ++rf) {
            f32x4 a = __builtin_amdgcn_mfma_f32_16x16x32_bf16(afrag[rf][0], B10, zero4, 0, 0, 0);
            acc1[rf] = __builtin_amdgcn_mfma_f32_16x16x32_bf16(afrag[rf][1], B11, a, 0, 0, 0);
        }
    };

    auto EXPPH = [&](float E0, float E1) {
        #pragma unroll
        for (int rf = 0; rf < 4; ++rf)
            #pragma unroll
            for (int r = 0; r < 4; ++r)
                s[rf][r] = fmaf(E0, __builtin_amdgcn_exp2f(acc0[rf][r]), s[rf][r]);
        #pragma unroll
        for (int rf = 0; rf < 4; ++rf)
            #pragma unroll
            for (int r = 0; r < 4; ++r)
                s[rf][r] = fmaf(E1, __builtin_amdgcn_exp2f(acc1[rf][r]), s[rf][r]);
    };

    short8 A00, A01, A10, A11, C00, C01, C10, C11;
    float Ea0, Ea1, Eb0, Eb1;

    if (nfull > 0) LOAD(A00, A01, A10, A11, Ea0, Ea1);
    for (int it = 0; it < nfull; it += 2) {
        if (it + 1 < nfull) LOAD(C00, C01, C10, C11, Eb0, Eb1);
        MFMAPH(A00, A01, A10, A11);
        EXPPH(Ea0, Ea1);
        if (it + 1 < nfull) {
            if (it + 2 < nfull) LOAD(A00, A01, A10, A11, Ea0, Ea1);
            MFMAPH(C00, C01, C10, C11);
            EXPPH(Eb0, Eb1);
        }
    }

    // masked tail (the single global-last iteration, if ragged)
    if (maskedLast) {
        const int itx  = it0 + cnt - 1;
        const int col0 = itx*128 + wave*32 + l15;
        const int col1 = col0 + 16;
        const int c0 = min(col0, N - 1);
        const int c1 = min(col1, N - 1);
        const short* q0 = Xb + (size_t)c0 * 64 + kq * 8;
        const short* q1 = Xb + (size_t)c1 * 64 + kq * 8;
        A00 = *(const short8*)(q0);
        A01 = *(const short8*)(q0 + 32);
        A10 = *(const short8*)(q1);
        A11 = *(const short8*)(q1 + 32);
        Ea0 = (col0 < N) ? Eq[c0] : 0.f;
        Ea1 = (col1 < N) ? Eq[c1] : 0.f;
        MFMAPH(A00, A01, A10, A11);
        EXPPH(Ea0, Ea1);
    }

    // reduce across the 16 lanes holding cols
    float t[4][4];
    #pragma unroll
    for (int rf = 0; rf < 4; ++rf)
        #pragma unroll
        for (int r = 0; r < 4; ++r) {
            float v = s[rf][r];
            v += __shfl_xor(v, 1);
            v += __shfl_xor(v, 2);
            v += __shfl_xor(v, 4);
            v += __shfl_xor(v, 8);
            t[rf][r] = v;
        }

    __shared__ float red[4][64];
    if (l15 == 0) {
        #pragma unroll
        for (int rf = 0; rf < 4; ++rf)
            #pragma unroll
            for (int r = 0; r < 4; ++r)
                red[wave][rf*16 + kq*4 + r] = t[rf][r];
    }
    __syncthreads();
    if (tid < 64) {
        partial[(size_t)split * M + rowbase + tid] =
            red[0][tid] + red[1][tid] + red[2][tid] + red[3][tid];
    }
}

__global__ __launch_bounds__(256) void kde_combine2(
    const float* __restrict__ ws, const float* __restrict__ x2q,
    float* __restrict__ out, int M, int nsplit, float coeff)
{
    int i = blockIdx.x * 256 + threadIdx.x;
    if (i < M) {
        float t = 0.f;
        for (int s = 0; s < nsplit; ++s) t += ws[(size_t)s * M + i];
        out[i] = fmaf(0.6931471805599453f, x2q[i], logf(t) + coeff);
    }
}

// ---------------------------------------------------------------------------
// Fallback fused fp32 path (only if ws too small) — proven round-1 structure.
// ---------------------------------------------------------------------------
__global__ __launch_bounds__(256) void kde_main_fb(
    const float* __restrict__ x, const float* __restrict__ Xg,
    const float* __restrict__ bw, float* __restrict__ ws,
    float* __restrict__ out, int M, int N, int nsplit, float coeff)
{
    const int tid  = threadIdx.x;
    const int lane = tid & 63;
    const int wave = tid >> 6;
    const int l15  = lane & 15;
    const int kq   = lane >> 4;
    const int rowbase = blockIdx.x * 64;
    const int split   = blockIdx.y;
    const int chunk   = (N + nsplit - 1) / nsplit;
    const int colstart = split * chunk;
    const int colend   = min(colstart + chunk, N);

    __shared__ float lds_x2[64];
    __shared__ float red[4][64];

    if (tid < 64) {
        const float* xp = x + (size_t)(rowbase + tid) * 64;
        float ssum = 0.f;
        #pragma unroll
        for (int k = 0; k < 16; ++k) {
            float4 v = ((const float4*)xp)[k];
            ssum += v.x*v.x + v.y*v.y + v.z*v.z + v.w*v.w;
        }
        lds_x2[tid] = ssum;
    }

    short8 afrag[4][2];
    #pragma unroll
    for (int rf = 0; rf < 4; ++rf) {
        const float* xp = x + (size_t)(rowbase + rf*16 + l15) * 64;
        #pragma unroll
        for (int kf = 0; kf < 2; ++kf) {
            const float* p = xp + kf*32 + kq*8;
            float4 v0 = ((const float4*)p)[0];
            float4 v1 = ((const float4*)p)[1];
            short8 a;
            a[0]=f2bf(v0.x); a[1]=f2bf(v0.y); a[2]=f2bf(v0.z); a[3]=f2bf(v0.w);
            a[4]=f2bf(v1.x); a[5]=f2bf(v1.y); a[6]=f2bf(v1.z); a[7]=f2bf(v1.w);
            afrag[rf][kf] = a;
        }
    }
    __syncthreads();

    float xa[4][4];
    #pragma unroll
    for (int rf = 0; rf < 4; ++rf)
        #pragma unroll
        for (int r = 0; r < 4; ++r)
            xa[rf][r] = lds_x2[rf*16 + kq*4 + r];

    const float b = bw[0];
    const float q = -1.4426950408889634f / (2.f * b * b);

    float s[4][4];
    #pragma unroll
    for (int rf = 0; rf < 4; ++rf)
        #pragma unroll
        for (int r = 0; r < 4; ++r) s[rf][r] = 0.f;

    const int span  = colend - colstart;
    const int niter = (span + 63) / 64;

    for (int it = 0; it < niter; ++it) {
        const int col  = colstart + it*64 + wave*16 + l15;
        const int colc = min(col, N - 1);
        const bool valid = (col < colend);

        const float* Xp = Xg + (size_t)colc * 64;
        float4 v0 = ((const float4*)(Xp + kq*8))[0];
        float4 v1 = ((const float4*)(Xp + kq*8))[1];
        float4 v2 = ((const float4*)(Xp + 32 + kq*8))[0];
        float4 v3 = ((const float4*)(Xp + 32 + kq*8))[1];

        float pa = v0.x*v0.x + v0.y*v0.y + v0.z*v0.z + v0.w*v0.w
                 + v1.x*v1.x + v1.y*v1.y + v1.z*v1.z + v1.w*v1.w
                 + v2.x*v2.x + v2.y*v2.y + v2.z*v2.z + v2.w*v2.w
                 + v3.x*v3.x + v3.y*v3.y + v3.z*v3.z + v3.w*v3.w;
        pa += __shfl_xor(pa, 16);
        pa += __shfl_xor(pa, 32);

        short8 bb0, bb1;
        bb0[0]=f2bf(v0.x); bb0[1]=f2bf(v0.y); bb0[2]=f2bf(v0.z); bb0[3]=f2bf(v0.w);
        bb0[4]=f2bf(v1.x); bb0[5]=f2bf(v1.y); bb0[6]=f2bf(v1.z); bb0[7]=f2bf(v1.w);
        bb1[0]=f2bf(v2.x); bb1[1]=f2bf(v2.y); bb1[2]=f2bf(v2.z); bb1[3]=f2bf(v2.w);
        bb1[4]=f2bf(v3.x); bb1[5]=f2bf(v3.y); bb1[6]=f2bf(v3.z); bb1[7]=f2bf(v3.w);

        #pragma unroll
        for (int rf = 0; rf < 4; ++rf) {
            f32x4 acc = {0.f, 0.f, 0.f, 0.f};
            acc = __builtin_amdgcn_mfma_f32_16x16x32_bf16(afrag[rf][0], bb0, acc, 0, 0, 0);
            acc = __builtin_amdgcn_mfma_f32_16x16x32_bf16(afrag[rf][1], bb1, acc, 0, 0, 0);
            #pragma unroll
            for (int r = 0; r < 4; ++r) {
                float d2 = fmaxf(xa[rf][r] + pa - 2.f*acc[r], 0.f);
                float e = valid ? __builtin_amdgcn_exp2f(d2 * q) : 0.f;
                s[rf][r] += e;
            }
        }
    }

    #pragma unroll
    for (int rf = 0; rf < 4; ++rf)
        #pragma unroll
        for (int r = 0; r < 4; ++r) {
            float v = s[rf][r];
            v += __shfl_xor(v, 1);
            v += __shfl_xor(v, 2);
            v += __shfl_xor(v, 4);
            v += __shfl_xor(v, 8);
            s[rf][r] = v;
        }

    __syncthreads();
    if (l15 == 0) {
        #pragma unroll
        for (int rf = 0; rf < 4; ++rf)
            #pragma unroll
            for (int r = 0; r < 4; ++r)
                red[wave][rf*16 + kq*4 + r] = s[rf][r];
    }
    __syncthreads();

    if (tid < 64) {
        float tot = red[0][tid] + red[1][tid] + red[2][tid] + red[3][tid];
        if (nsplit == 1) out[rowbase + tid] = logf(tot) + coeff;
        else             ws[(size_t)split * M + rowbase + tid] = tot;
    }
}

__global__ __launch_bounds__(256) void kde_combine_fb(
    const float* __restrict__ ws, float* __restrict__ out,
    int M, int nsplit, float coeff)
{
    int i = blockIdx.x * 256 + threadIdx.x;
    if (i < M) {
        float t = 0.f;
        for (int s = 0; s < nsplit; ++s) t += ws[(size_t)s * M + i];
        out[i] = logf(t) + coeff;
    }
}

extern "C" void kernel_launch(void* const* d_in, const int* in_sizes, int n_in,
                              void* d_out, int out_size, void* d_ws, size_t ws_size,
                              hipStream_t stream) {
    const float* x  = (const float*)d_in[0];
    const float* Xg = (const float*)d_in[1];
    const float* bw = (const float*)d_in[2];
    float* out = (float*)d_out;

    const int M = in_sizes[0] / 64;
    const int N = in_sizes[1] / 64;
    const float coeff = -logf((float)N) - logf(2.f * (float)M_PI) * 32.f;

    auto align256 = [](size_t v) { return (v + 255) & ~(size_t)255; };
    const size_t szXb   = align256((size_t)N * 64 * sizeof(short));
    const size_t szxb   = align256((size_t)M * 64 * sizeof(short));
    const size_t szEq   = align256((size_t)N * sizeof(float));
    const size_t szx2q  = align256((size_t)M * sizeof(float));
    const size_t szPart = align256((size_t)NSPLIT * M * sizeof(float));
    const size_t need   = szXb + szxb + szEq + szx2q + szPart;

    if (ws_size >= need) {
        char* w = (char*)d_ws;
        short* Xb   = (short*)(w);
        short* xb   = (short*)(w + szXb);
        float* Eq   = (float*)(w + szXb + szxb);
        float* x2q  = (float*)(w + szXb + szxb + szEq);
        float* part = (float*)(w + szXb + szxb + szEq + szx2q);

        const int totalRows = M + N;
        kde_prep<<<(totalRows * 8 + 255) / 256, 256, 0, stream>>>(
            x, Xg, bw, Xb, Eq, xb, x2q, M, N);

        dim3 grid(M / 64, NSPLIT);
        kde_main4<<<grid, 256, 0, stream>>>(Xb, Eq, xb, part, M, N);

        kde_combine2<<<(M + 255) / 256, 256, 0, stream>>>(part, x2q, out, M, NSPLIT, coeff);
    } else {
        int nsplit = 8;
        if (ws_size < (size_t)nsplit * M * sizeof(float)) nsplit = 1;
        dim3 grid(M / 64, nsplit);
        kde_main_fb<<<grid, 256, 0, stream>>>(x, Xg, bw, (float*)d_ws, out, M, N, nsplit, coeff);
        if (nsplit > 1)
            kde_combine_fb<<<(M + 255) / 256, 256, 0, stream>>>((const float*)d_ws, out, M, nsplit, coeff);
    }
}

// Round 6
// 58.818 us; speedup vs baseline: 2.9814x; 1.3159x over previous
//
#include <hip/hip_runtime.h>
#include <hip/hip_bf16.h>
#include <math.h>

#define NSPLIT 24
#define MROWS  128

typedef __attribute__((ext_vector_type(8))) short short8;
typedef __attribute__((ext_vector_type(4))) float f32x4;

__device__ __forceinline__ short f2bf(float f) {
    __hip_bfloat16 h = __float2bfloat16(f);
    return __builtin_bit_cast(short, h);
}

// ---------------------------------------------------------------------------
// Preprocess:
//   X rows -> Xb bf16 (unscaled)  + Eq[col] = exp2(q*||X||^2)  (f32)
//   x rows -> xb bf16 scaled by -2q + x2q[row] = q*||x||^2     (f32)
// q = -log2(e)/(2 b^2).  exp(-d2/(2b^2)) = exp2(q*x2) * Eq[col] * exp2((-2q x)·X)
// ---------------------------------------------------------------------------
__global__ __launch_bounds__(256) void kde_prep(
    const float* __restrict__ x, const float* __restrict__ Xg,
    const float* __restrict__ bw,
    short* __restrict__ Xb, float* __restrict__ Eq,
    short* __restrict__ xb, float* __restrict__ x2q, int M, int N)
{
    const int gid = blockIdx.x * 256 + threadIdx.x;
    const int row = gid >> 3;
    const int sub = gid & 7;
    if (row >= M + N) return;

    const float b = bw[0];
    const float q = -1.4426950408889634f / (2.f * b * b);
    const float s2q = -2.f * q;

    const float* src;
    short* dst;
    float sc;
    if (row < N) { src = Xg + (size_t)row * 64;     dst = Xb + (size_t)row * 64;     sc = 1.f; }
    else         { src = x  + (size_t)(row-N) * 64; dst = xb + (size_t)(row-N) * 64; sc = s2q; }

    float4 v0 = ((const float4*)(src + sub * 8))[0];
    float4 v1 = ((const float4*)(src + sub * 8))[1];

    float ss = v0.x*v0.x + v0.y*v0.y + v0.z*v0.z + v0.w*v0.w
             + v1.x*v1.x + v1.y*v1.y + v1.z*v1.z + v1.w*v1.w;
    ss += __shfl_xor(ss, 1);
    ss += __shfl_xor(ss, 2);
    ss += __shfl_xor(ss, 4);

    short8 o;
    o[0]=f2bf(v0.x*sc); o[1]=f2bf(v0.y*sc); o[2]=f2bf(v0.z*sc); o[3]=f2bf(v0.w*sc);
    o[4]=f2bf(v1.x*sc); o[5]=f2bf(v1.y*sc); o[6]=f2bf(v1.z*sc); o[7]=f2bf(v1.w*sc);
    *(short8*)(dst + sub * 8) = o;

    if (sub == 0) {
        if (row < N) Eq[row] = exp2f(ss * q);
        else         x2q[row - N] = ss * q;
    }
}

// ---------------------------------------------------------------------------
// Main: 128 x-rows per block (8 rf fragments), 4 waves; each wave owns 16
// cols/iter -> block covers 64 cols/iter. Same compute per iter as before
// but HALF the B bytes per lane (2x arithmetic intensity), and X is swept
// 32x instead of 64x (half the L2/L3 traffic).
// Prefetch is double-buffered and PINNED with sched_barrier(0) so the
// scheduler cannot sink the loads into the compute phase.
// ---------------------------------------------------------------------------
__global__ __launch_bounds__(256, 2) void kde_main5(
    const short* __restrict__ Xb, const float* __restrict__ Eq,
    const short* __restrict__ xb,
    float* __restrict__ partial, int M, int N)
{
    const int tid  = threadIdx.x;
    const int lane = tid & 63;
    const int wave = tid >> 6;
    const int l15  = lane & 15;
    const int kq   = lane >> 4;
    const int rowbase = blockIdx.x * MROWS;
    const int split   = blockIdx.y;

    const int T    = (N + 63) >> 6;           // total 64-col iterations
    const int base = T / NSPLIT;
    const int remu = T % NSPLIT;
    const int it0  = split * base + min(split, remu);
    const int cnt  = base + (split < remu ? 1 : 0);
    const bool maskedLast = (it0 + cnt == T) && ((N & 63) != 0);
    const int nfull = cnt - (maskedLast ? 1 : 0);

    // A fragments (bf16, pre-scaled by -2q): row = lane&15, k = 8*(lane>>4)+i
    short8 afrag[8][2];
    #pragma unroll
    for (int rf = 0; rf < 8; ++rf) {
        const short* p = xb + (size_t)(rowbase + rf*16 + l15) * 64 + kq * 8;
        afrag[rf][0] = *(const short8*)(p);
        afrag[rf][1] = *(const short8*)(p + 32);
    }

    const f32x4 zero4 = {0.f, 0.f, 0.f, 0.f};

    float s[8][4];
    #pragma unroll
    for (int rf = 0; rf < 8; ++rf)
        #pragma unroll
        for (int r = 0; r < 4; ++r) s[rf][r] = 0.f;

    // streaming pointers (per-iter stride: 64 cols)
    const short* pB = Xb + (size_t)(it0*64 + wave*16 + l15) * 64 + kq * 8;
    const float* pE = Eq + it0*64 + wave*16 + l15;
    const size_t strideB = (size_t)64 * 64;

    f32x4 acc[8];
    short8 Ba0, Ba1, Bb0, Bb1;
    float  Ea, Eb;

    auto LOADA = [&]() {
        Ba0 = *(const short8*)(pB);
        Ba1 = *(const short8*)(pB + 32);
        Ea  = *pE;
        pB += strideB; pE += 64;
    };
    auto LOADB = [&]() {
        Bb0 = *(const short8*)(pB);
        Bb1 = *(const short8*)(pB + 32);
        Eb  = *pE;
        pB += strideB; pE += 64;
    };

    auto MFMAPH = [&](short8 B0, short8 B1) {
        #pragma unroll
        for (int rf = 0; rf < 8; ++rf) {
            f32x4 a = __builtin_amdgcn_mfma_f32_16x16x32_bf16(afrag[rf][0], B0, zero4, 0, 0, 0);
            acc[rf] = __builtin_amdgcn_mfma_f32_16x16x32_bf16(afrag[rf][1], B1, a, 0, 0, 0);
        }
    };
    auto EXPPH = [&](float E) {
        #pragma unroll
        for (int rf = 0; rf < 8; ++rf)
            #pragma unroll
            for (int r = 0; r < 4; ++r)
                s[rf][r] = fmaf(E, __builtin_amdgcn_exp2f(acc[rf][r]), s[rf][r]);
    };

    if (nfull > 0) LOADA();
    for (int it = 0; it < nfull; it += 2) {
        if (it + 1 < nfull) LOADB();
        __builtin_amdgcn_sched_barrier(0);      // pin prefetch above compute
        MFMAPH(Ba0, Ba1);
        EXPPH(Ea);
        if (it + 1 < nfull) {
            if (it + 2 < nfull) LOADA();
            __builtin_amdgcn_sched_barrier(0);
            MFMAPH(Bb0, Bb1);
            EXPPH(Eb);
        }
    }

    // masked tail (single global-last iteration, if ragged)
    if (maskedLast) {
        const int col = (it0 + cnt - 1)*64 + wave*16 + l15;
        const int c   = min(col, N - 1);
        const short* p = Xb + (size_t)c * 64 + kq * 8;
        Ba0 = *(const short8*)(p);
        Ba1 = *(const short8*)(p + 32);
        Ea  = (col < N) ? Eq[c] : 0.f;
        MFMAPH(Ba0, Ba1);
        EXPPH(Ea);
    }

    // reduce across the 16 lanes holding cols
    float t[8][4];
    #pragma unroll
    for (int rf = 0; rf < 8; ++rf)
        #pragma unroll
        for (int r = 0; r < 4; ++r) {
            float v = s[rf][r];
            v += __shfl_xor(v, 1);
            v += __shfl_xor(v, 2);
            v += __shfl_xor(v, 4);
            v += __shfl_xor(v, 8);
            t[rf][r] = v;
        }

    __shared__ float red[4][MROWS];
    if (l15 == 0) {
        #pragma unroll
        for (int rf = 0; rf < 8; ++rf)
            #pragma unroll
            for (int r = 0; r < 4; ++r)
                red[wave][rf*16 + kq*4 + r] = t[rf][r];
    }
    __syncthreads();
    if (tid < MROWS) {
        partial[(size_t)split * M + rowbase + tid] =
            red[0][tid] + red[1][tid] + red[2][tid] + red[3][tid];
    }
}

__global__ __launch_bounds__(256) void kde_combine2(
    const float* __restrict__ ws, const float* __restrict__ x2q,
    float* __restrict__ out, int M, int nsplit, float coeff)
{
    int i = blockIdx.x * 256 + threadIdx.x;
    if (i < M) {
        float t = 0.f;
        for (int s = 0; s < nsplit; ++s) t += ws[(size_t)s * M + i];
        out[i] = fmaf(0.6931471805599453f, x2q[i], logf(t) + coeff);
    }
}

// ---------------------------------------------------------------------------
// Fallback fused fp32 path (only if ws too small) — proven round-1 structure.
// ---------------------------------------------------------------------------
__global__ __launch_bounds__(256) void kde_main_fb(
    const float* __restrict__ x, const float* __restrict__ Xg,
    const float* __restrict__ bw, float* __restrict__ ws,
    float* __restrict__ out, int M, int N, int nsplit, float coeff)
{
    const int tid  = threadIdx.x;
    const int lane = tid & 63;
    const int wave = tid >> 6;
    const int l15  = lane & 15;
    const int kq   = lane >> 4;
    const int rowbase = blockIdx.x * 64;
    const int split   = blockIdx.y;
    const int chunk   = (N + nsplit - 1) / nsplit;
    const int colstart = split * chunk;
    const int colend   = min(colstart + chunk, N);

    __shared__ float lds_x2[64];
    __shared__ float red[4][64];

    if (tid < 64) {
        const float* xp = x + (size_t)(rowbase + tid) * 64;
        float ssum = 0.f;
        #pragma unroll
        for (int k = 0; k < 16; ++k) {
            float4 v = ((const float4*)xp)[k];
            ssum += v.x*v.x + v.y*v.y + v.z*v.z + v.w*v.w;
        }
        lds_x2[tid] = ssum;
    }

    short8 afrag[4][2];
    #pragma unroll
    for (int rf = 0; rf < 4; ++rf) {
        const float* xp = x + (size_t)(rowbase + rf*16 + l15) * 64;
        #pragma unroll
        for (int kf = 0; kf < 2; ++kf) {
            const float* p = xp + kf*32 + kq*8;
            float4 v0 = ((const float4*)p)[0];
            float4 v1 = ((const float4*)p)[1];
            short8 a;
            a[0]=f2bf(v0.x); a[1]=f2bf(v0.y); a[2]=f2bf(v0.z); a[3]=f2bf(v0.w);
            a[4]=f2bf(v1.x); a[5]=f2bf(v1.y); a[6]=f2bf(v1.z); a[7]=f2bf(v1.w);
            afrag[rf][kf] = a;
        }
    }
    __syncthreads();

    float xa[4][4];
    #pragma unroll
    for (int rf = 0; rf < 4; ++rf)
        #pragma unroll
        for (int r = 0; r < 4; ++r)
            xa[rf][r] = lds_x2[rf*16 + kq*4 + r];

    const float b = bw[0];
    const float q = -1.4426950408889634f / (2.f * b * b);

    float s[4][4];
    #pragma unroll
    for (int rf = 0; rf < 4; ++rf)
        #pragma unroll
        for (int r = 0; r < 4; ++r) s[rf][r] = 0.f;

    const int span  = colend - colstart;
    const int niter = (span + 63) / 64;

    for (int it = 0; it < niter; ++it) {
        const int col  = colstart + it*64 + wave*16 + l15;
        const int colc = min(col, N - 1);
        const bool valid = (col < colend);

        const float* Xp = Xg + (size_t)colc * 64;
        float4 v0 = ((const float4*)(Xp + kq*8))[0];
        float4 v1 = ((const float4*)(Xp + kq*8))[1];
        float4 v2 = ((const float4*)(Xp + 32 + kq*8))[0];
        float4 v3 = ((const float4*)(Xp + 32 + kq*8))[1];

        float pa = v0.x*v0.x + v0.y*v0.y + v0.z*v0.z + v0.w*v0.w
                 + v1.x*v1.x + v1.y*v1.y + v1.z*v1.z + v1.w*v1.w
                 + v2.x*v2.x + v2.y*v2.y + v2.z*v2.z + v2.w*v2.w
                 + v3.x*v3.x + v3.y*v3.y + v3.z*v3.z + v3.w*v3.w;
        pa += __shfl_xor(pa, 16);
        pa += __shfl_xor(pa, 32);

        short8 bb0, bb1;
        bb0[0]=f2bf(v0.x); bb0[1]=f2bf(v0.y); bb0[2]=f2bf(v0.z); bb0[3]=f2bf(v0.w);
        bb0[4]=f2bf(v1.x); bb0[5]=f2bf(v1.y); bb0[6]=f2bf(v1.z); bb0[7]=f2bf(v1.w);
        bb1[0]=f2bf(v2.x); bb1[1]=f2bf(v2.y); bb1[2]=f2bf(v2.z); bb1[3]=f2bf(v2.w);
        bb1[4]=f2bf(v3.x); bb1[5]=f2bf(v3.y); bb1[6]=f2bf(v3.z); bb1[7]=f2bf(v3.w);

        #pragma unroll
        for (int rf = 0; rf < 4; ++rf) {
            f32x4 acc = {0.f, 0.f, 0.f, 0.f};
            acc = __builtin_amdgcn_mfma_f32_16x16x32_bf16(afrag[rf][0], bb0, acc, 0, 0, 0);
            acc = __builtin_amdgcn_mfma_f32_16x16x32_bf16(afrag[rf][1], bb1, acc, 0, 0, 0);
            #pragma unroll
            for (int r = 0; r < 4; ++r) {
                float d2 = fmaxf(xa[rf][r] + pa - 2.f*acc[r], 0.f);
                float e = valid ? __builtin_amdgcn_exp2f(d2 * q) : 0.f;
                s[rf][r] += e;
            }
        }
    }

    #pragma unroll
    for (int rf = 0; rf < 4; ++rf)
        #pragma unroll
        for (int r = 0; r < 4; ++r) {
            float v = s[rf][r];
            v += __shfl_xor(v, 1);
            v += __shfl_xor(v, 2);
            v += __shfl_xor(v, 4);
            v += __shfl_xor(v, 8);
            s[rf][r] = v;
        }

    __syncthreads();
    if (l15 == 0) {
        #pragma unroll
        for (int rf = 0; rf < 4; ++rf)
            #pragma unroll
            for (int r = 0; r < 4; ++r)
                red[wave][rf*16 + kq*4 + r] = s[rf][r];
    }
    __syncthreads();

    if (tid < 64) {
        float tot = red[0][tid] + red[1][tid] + red[2][tid] + red[3][tid];
        if (nsplit == 1) out[rowbase + tid] = logf(tot) + coeff;
        else             ws[(size_t)split * M + rowbase + tid] = tot;
    }
}

__global__ __launch_bounds__(256) void kde_combine_fb(
    const float* __restrict__ ws, float* __restrict__ out,
    int M, int nsplit, float coeff)
{
    int i = blockIdx.x * 256 + threadIdx.x;
    if (i < M) {
        float t = 0.f;
        for (int s = 0; s < nsplit; ++s) t += ws[(size_t)s * M + i];
        out[i] = logf(t) + coeff;
    }
}

extern "C" void kernel_launch(void* const* d_in, const int* in_sizes, int n_in,
                              void* d_out, int out_size, void* d_ws, size_t ws_size,
                              hipStream_t stream) {
    const float* x  = (const float*)d_in[0];
    const float* Xg = (const float*)d_in[1];
    const float* bw = (const float*)d_in[2];
    float* out = (float*)d_out;

    const int M = in_sizes[0] / 64;
    const int N = in_sizes[1] / 64;
    const float coeff = -logf((float)N) - logf(2.f * (float)M_PI) * 32.f;

    auto align256 = [](size_t v) { return (v + 255) & ~(size_t)255; };
    const size_t szXb   = align256((size_t)N * 64 * sizeof(short));
    const size_t szxb   = align256((size_t)M * 64 * sizeof(short));
    const size_t szEq   = align256((size_t)N * sizeof(float));
    const size_t szx2q  = align256((size_t)M * sizeof(float));
    const size_t szPart = align256((size_t)NSPLIT * M * sizeof(float));
    const size_t need   = szXb + szxb + szEq + szx2q + szPart;

    if (ws_size >= need && (M % MROWS) == 0) {
        char* w = (char*)d_ws;
        short* Xb   = (short*)(w);
        short* xb   = (short*)(w + szXb);
        float* Eq   = (float*)(w + szXb + szxb);
        float* x2q  = (float*)(w + szXb + szxb + szEq);
        float* part = (float*)(w + szXb + szxb + szEq + szx2q);

        const int totalRows = M + N;
        kde_prep<<<(totalRows * 8 + 255) / 256, 256, 0, stream>>>(
            x, Xg, bw, Xb, Eq, xb, x2q, M, N);

        dim3 grid(M / MROWS, NSPLIT);
        kde_main5<<<grid, 256, 0, stream>>>(Xb, Eq, xb, part, M, N);

        kde_combine2<<<(M + 255) / 256, 256, 0, stream>>>(part, x2q, out, M, NSPLIT, coeff);
    } else {
        int nsplit = 8;
        if (ws_size < (size_t)nsplit * M * sizeof(float)) nsplit = 1;
        dim3 grid(M / 64, nsplit);
        kde_main_fb<<<grid, 256, 0, stream>>>(x, Xg, bw, (float*)d_ws, out, M, N, nsplit, coeff);
        if (nsplit > 1)
            kde_combine_fb<<<(M + 255) / 256, 256, 0, stream>>>((const float*)d_ws, out, M, nsplit, coeff);
    }
}

// Round 7
// 56.498 us; speedup vs baseline: 3.1038x; 1.0411x over previous
//
#include <hip/hip_runtime.h>
#include <hip/hip_bf16.h>
#include <math.h>

#define NSPLIT 24          // must be divisible by 8 for the XCD swizzle
#define MROWS  128

typedef __attribute__((ext_vector_type(8))) short short8;
typedef __attribute__((ext_vector_type(4))) float f32x4;

__device__ __forceinline__ short f2bf(float f) {
    __hip_bfloat16 h = __float2bfloat16(f);
    return __builtin_bit_cast(short, h);
}

// ---------------------------------------------------------------------------
// Preprocess:
//   X rows -> Xb bf16 (unscaled)  + Eq[col] = exp2(q*||X||^2)  (f32)
//   x rows -> xb bf16 scaled by -2q + x2q[row] = q*||x||^2     (f32)
// q = -log2(e)/(2 b^2).  exp(-d2/(2b^2)) = exp2(q*x2) * Eq[col] * exp2((-2q x)·X)
// ---------------------------------------------------------------------------
__global__ __launch_bounds__(256) void kde_prep(
    const float* __restrict__ x, const float* __restrict__ Xg,
    const float* __restrict__ bw,
    short* __restrict__ Xb, float* __restrict__ Eq,
    short* __restrict__ xb, float* __restrict__ x2q, int M, int N)
{
    const int gid = blockIdx.x * 256 + threadIdx.x;
    const int row = gid >> 3;
    const int sub = gid & 7;
    if (row >= M + N) return;

    const float b = bw[0];
    const float q = -1.4426950408889634f / (2.f * b * b);
    const float s2q = -2.f * q;

    const float* src;
    short* dst;
    float sc;
    if (row < N) { src = Xg + (size_t)row * 64;     dst = Xb + (size_t)row * 64;     sc = 1.f; }
    else         { src = x  + (size_t)(row-N) * 64; dst = xb + (size_t)(row-N) * 64; sc = s2q; }

    float4 v0 = ((const float4*)(src + sub * 8))[0];
    float4 v1 = ((const float4*)(src + sub * 8))[1];

    float ss = v0.x*v0.x + v0.y*v0.y + v0.z*v0.z + v0.w*v0.w
             + v1.x*v1.x + v1.y*v1.y + v1.z*v1.z + v1.w*v1.w;
    ss += __shfl_xor(ss, 1);
    ss += __shfl_xor(ss, 2);
    ss += __shfl_xor(ss, 4);

    short8 o;
    o[0]=f2bf(v0.x*sc); o[1]=f2bf(v0.y*sc); o[2]=f2bf(v0.z*sc); o[3]=f2bf(v0.w*sc);
    o[4]=f2bf(v1.x*sc); o[5]=f2bf(v1.y*sc); o[6]=f2bf(v1.z*sc); o[7]=f2bf(v1.w*sc);
    *(short8*)(dst + sub * 8) = o;

    if (sub == 0) {
        if (row < N) Eq[row] = exp2f(ss * q);
        else         x2q[row - N] = ss * q;
    }
}

// ---------------------------------------------------------------------------
// Main: 128 x-rows per block (8 rf fragments), 4 waves; each wave owns 16
// cols/iter -> block covers 64 cols/iter.
//
// XCD-aware block placement: linear blockIdx L -> (split, mblock) such that
// XCD k (round-robin L%8) concurrently runs ALL mblocks of split k (then
// k+8, k+16). Per-XCD L2 working set = 1-2 split chunks (~0.5 MB) instead
// of ~16 chunks (4.3 MB) -> B loads become L2 hits, X fetched from HBM once.
//   split  = (L & 7) + 8 * (L / (8*NB))
//   mblock = (L >> 3) % NB            (bijective for gridDim = NB*NSPLIT)
// ---------------------------------------------------------------------------
__global__ __launch_bounds__(256, 2) void kde_main6(
    const short* __restrict__ Xb, const float* __restrict__ Eq,
    const short* __restrict__ xb,
    float* __restrict__ partial, int M, int N, int NB)
{
    const int tid  = threadIdx.x;
    const int lane = tid & 63;
    const int wave = tid >> 6;
    const int l15  = lane & 15;
    const int kq   = lane >> 4;

    const int L      = blockIdx.x;
    const int split  = (L & 7) + 8 * (L / (8 * NB));
    const int mblock = (L >> 3) % NB;
    const int rowbase = mblock * MROWS;

    const int T    = (N + 63) >> 6;           // total 64-col iterations
    const int base = T / NSPLIT;
    const int remu = T % NSPLIT;
    const int it0  = split * base + min(split, remu);
    const int cnt  = base + (split < remu ? 1 : 0);
    const bool maskedLast = (it0 + cnt == T) && ((N & 63) != 0);
    const int nfull = cnt - (maskedLast ? 1 : 0);

    // A fragments (bf16, pre-scaled by -2q): row = lane&15, k = 8*(lane>>4)+i
    short8 afrag[8][2];
    #pragma unroll
    for (int rf = 0; rf < 8; ++rf) {
        const short* p = xb + (size_t)(rowbase + rf*16 + l15) * 64 + kq * 8;
        afrag[rf][0] = *(const short8*)(p);
        afrag[rf][1] = *(const short8*)(p + 32);
    }

    const f32x4 zero4 = {0.f, 0.f, 0.f, 0.f};

    float s[8][4];
    #pragma unroll
    for (int rf = 0; rf < 8; ++rf)
        #pragma unroll
        for (int r = 0; r < 4; ++r) s[rf][r] = 0.f;

    // streaming pointers (per-iter stride: 64 cols)
    const short* pB = Xb + (size_t)(it0*64 + wave*16 + l15) * 64 + kq * 8;
    const float* pE = Eq + it0*64 + wave*16 + l15;
    const size_t strideB = (size_t)64 * 64;

    f32x4 acc[8];
    short8 Ba0, Ba1, Bb0, Bb1;
    float  Ea, Eb;

    auto LOADA = [&]() {
        Ba0 = *(const short8*)(pB);
        Ba1 = *(const short8*)(pB + 32);
        Ea  = *pE;
        pB += strideB; pE += 64;
    };
    auto LOADB = [&]() {
        Bb0 = *(const short8*)(pB);
        Bb1 = *(const short8*)(pB + 32);
        Eb  = *pE;
        pB += strideB; pE += 64;
    };

    auto MFMAPH = [&](short8 B0, short8 B1) {
        #pragma unroll
        for (int rf = 0; rf < 8; ++rf) {
            f32x4 a = __builtin_amdgcn_mfma_f32_16x16x32_bf16(afrag[rf][0], B0, zero4, 0, 0, 0);
            acc[rf] = __builtin_amdgcn_mfma_f32_16x16x32_bf16(afrag[rf][1], B1, a, 0, 0, 0);
        }
    };
    auto EXPPH = [&](float E) {
        #pragma unroll
        for (int rf = 0; rf < 8; ++rf)
            #pragma unroll
            for (int r = 0; r < 4; ++r)
                s[rf][r] = fmaf(E, __builtin_amdgcn_exp2f(acc[rf][r]), s[rf][r]);
    };

    if (nfull > 0) LOADA();
    for (int it = 0; it < nfull; it += 2) {
        if (it + 1 < nfull) LOADB();
        __builtin_amdgcn_sched_barrier(0);      // pin prefetch above compute
        MFMAPH(Ba0, Ba1);
        EXPPH(Ea);
        if (it + 1 < nfull) {
            if (it + 2 < nfull) LOADA();
            __builtin_amdgcn_sched_barrier(0);
            MFMAPH(Bb0, Bb1);
            EXPPH(Eb);
        }
    }

    // masked tail (single global-last iteration, if ragged)
    if (maskedLast) {
        const int col = (it0 + cnt - 1)*64 + wave*16 + l15;
        const int c   = min(col, N - 1);
        const short* p = Xb + (size_t)c * 64 + kq * 8;
        Ba0 = *(const short8*)(p);
        Ba1 = *(const short8*)(p + 32);
        Ea  = (col < N) ? Eq[c] : 0.f;
        MFMAPH(Ba0, Ba1);
        EXPPH(Ea);
    }

    // reduce across the 16 lanes holding cols
    float t[8][4];
    #pragma unroll
    for (int rf = 0; rf < 8; ++rf)
        #pragma unroll
        for (int r = 0; r < 4; ++r) {
            float v = s[rf][r];
            v += __shfl_xor(v, 1);
            v += __shfl_xor(v, 2);
            v += __shfl_xor(v, 4);
            v += __shfl_xor(v, 8);
            t[rf][r] = v;
        }

    __shared__ float red[4][MROWS];
    if (l15 == 0) {
        #pragma unroll
        for (int rf = 0; rf < 8; ++rf)
            #pragma unroll
            for (int r = 0; r < 4; ++r)
                red[wave][rf*16 + kq*4 + r] = t[rf][r];
    }
    __syncthreads();
    if (tid < MROWS) {
        partial[(size_t)split * M + rowbase + tid] =
            red[0][tid] + red[1][tid] + red[2][tid] + red[3][tid];
    }
}

__global__ __launch_bounds__(256) void kde_combine2(
    const float* __restrict__ ws, const float* __restrict__ x2q,
    float* __restrict__ out, int M, int nsplit, float coeff)
{
    int i = blockIdx.x * 256 + threadIdx.x;
    if (i < M) {
        float t = 0.f;
        for (int s = 0; s < nsplit; ++s) t += ws[(size_t)s * M + i];
        out[i] = fmaf(0.6931471805599453f, x2q[i], logf(t) + coeff);
    }
}

// ---------------------------------------------------------------------------
// Fallback fused fp32 path (only if ws too small or M not tile-divisible).
// ---------------------------------------------------------------------------
__global__ __launch_bounds__(256) void kde_main_fb(
    const float* __restrict__ x, const float* __restrict__ Xg,
    const float* __restrict__ bw, float* __restrict__ ws,
    float* __restrict__ out, int M, int N, int nsplit, float coeff)
{
    const int tid  = threadIdx.x;
    const int lane = tid & 63;
    const int wave = tid >> 6;
    const int l15  = lane & 15;
    const int kq   = lane >> 4;
    const int rowbase = blockIdx.x * 64;
    const int split   = blockIdx.y;
    const int chunk   = (N + nsplit - 1) / nsplit;
    const int colstart = split * chunk;
    const int colend   = min(colstart + chunk, N);

    __shared__ float lds_x2[64];
    __shared__ float red[4][64];

    if (tid < 64) {
        const float* xp = x + (size_t)(rowbase + tid) * 64;
        float ssum = 0.f;
        #pragma unroll
        for (int k = 0; k < 16; ++k) {
            float4 v = ((const float4*)xp)[k];
            ssum += v.x*v.x + v.y*v.y + v.z*v.z + v.w*v.w;
        }
        lds_x2[tid] = ssum;
    }

    short8 afrag[4][2];
    #pragma unroll
    for (int rf = 0; rf < 4; ++rf) {
        const float* xp = x + (size_t)(rowbase + rf*16 + l15) * 64;
        #pragma unroll
        for (int kf = 0; kf < 2; ++kf) {
            const float* p = xp + kf*32 + kq*8;
            float4 v0 = ((const float4*)p)[0];
            float4 v1 = ((const float4*)p)[1];
            short8 a;
            a[0]=f2bf(v0.x); a[1]=f2bf(v0.y); a[2]=f2bf(v0.z); a[3]=f2bf(v0.w);
            a[4]=f2bf(v1.x); a[5]=f2bf(v1.y); a[6]=f2bf(v1.z); a[7]=f2bf(v1.w);
            afrag[rf][kf] = a;
        }
    }
    __syncthreads();

    float xa[4][4];
    #pragma unroll
    for (int rf = 0; rf < 4; ++rf)
        #pragma unroll
        for (int r = 0; r < 4; ++r)
            xa[rf][r] = lds_x2[rf*16 + kq*4 + r];

    const float b = bw[0];
    const float q = -1.4426950408889634f / (2.f * b * b);

    float s[4][4];
    #pragma unroll
    for (int rf = 0; rf < 4; ++rf)
        #pragma unroll
        for (int r = 0; r < 4; ++r) s[rf][r] = 0.f;

    const int span  = colend - colstart;
    const int niter = (span + 63) / 64;

    for (int it = 0; it < niter; ++it) {
        const int col  = colstart + it*64 + wave*16 + l15;
        const int colc = min(col, N - 1);
        const bool valid = (col < colend);

        const float* Xp = Xg + (size_t)colc * 64;
        float4 v0 = ((const float4*)(Xp + kq*8))[0];
        float4 v1 = ((const float4*)(Xp + kq*8))[1];
        float4 v2 = ((const float4*)(Xp + 32 + kq*8))[0];
        float4 v3 = ((const float4*)(Xp + 32 + kq*8))[1];

        float pa = v0.x*v0.x + v0.y*v0.y + v0.z*v0.z + v0.w*v0.w
                 + v1.x*v1.x + v1.y*v1.y + v1.z*v1.z + v1.w*v1.w
                 + v2.x*v2.x + v2.y*v2.y + v2.z*v2.z + v2.w*v2.w
                 + v3.x*v3.x + v3.y*v3.y + v3.z*v3.z + v3.w*v3.w;
        pa += __shfl_xor(pa, 16);
        pa += __shfl_xor(pa, 32);

        short8 bb0, bb1;
        bb0[0]=f2bf(v0.x); bb0[1]=f2bf(v0.y); bb0[2]=f2bf(v0.z); bb0[3]=f2bf(v0.w);
        bb0[4]=f2bf(v1.x); bb0[5]=f2bf(v1.y); bb0[6]=f2bf(v1.z); bb0[7]=f2bf(v1.w);
        bb1[0]=f2bf(v2.x); bb1[1]=f2bf(v2.y); bb1[2]=f2bf(v2.z); bb1[3]=f2bf(v2.w);
        bb1[4]=f2bf(v3.x); bb1[5]=f2bf(v3.y); bb1[6]=f2bf(v3.z); bb1[7]=f2bf(v3.w);

        #pragma unroll
        for (int rf = 0; rf < 4; ++rf) {
            f32x4 acc = {0.f, 0.f, 0.f, 0.f};
            acc = __builtin_amdgcn_mfma_f32_16x16x32_bf16(afrag[rf][0], bb0, acc, 0, 0, 0);
            acc = __builtin_amdgcn_mfma_f32_16x16x32_bf16(afrag[rf][1], bb1, acc, 0, 0, 0);
            #pragma unroll
            for (int r = 0; r < 4; ++r) {
                float d2 = fmaxf(xa[rf][r] + pa - 2.f*acc[r], 0.f);
                float e = valid ? __builtin_amdgcn_exp2f(d2 * q) : 0.f;
                s[rf][r] += e;
            }
        }
    }

    #pragma unroll
    for (int rf = 0; rf < 4; ++rf)
        #pragma unroll
        for (int r = 0; r < 4; ++r) {
            float v = s[rf][r];
            v += __shfl_xor(v, 1);
            v += __shfl_xor(v, 2);
            v += __shfl_xor(v, 4);
            v += __shfl_xor(v, 8);
            s[rf][r] = v;
        }

    __syncthreads();
    if (l15 == 0) {
        #pragma unroll
        for (int rf = 0; rf < 4; ++rf)
            #pragma unroll
            for (int r = 0; r < 4; ++r)
                red[wave][rf*16 + kq*4 + r] = s[rf][r];
    }
    __syncthreads();

    if (tid < 64) {
        float tot = red[0][tid] + red[1][tid] + red[2][tid] + red[3][tid];
        if (nsplit == 1) out[rowbase + tid] = logf(tot) + coeff;
        else             ws[(size_t)split * M + rowbase + tid] = tot;
    }
}

__global__ __launch_bounds__(256) void kde_combine_fb(
    const float* __restrict__ ws, float* __restrict__ out,
    int M, int nsplit, float coeff)
{
    int i = blockIdx.x * 256 + threadIdx.x;
    if (i < M) {
        float t = 0.f;
        for (int s = 0; s < nsplit; ++s) t += ws[(size_t)s * M + i];
        out[i] = logf(t) + coeff;
    }
}

extern "C" void kernel_launch(void* const* d_in, const int* in_sizes, int n_in,
                              void* d_out, int out_size, void* d_ws, size_t ws_size,
                              hipStream_t stream) {
    const float* x  = (const float*)d_in[0];
    const float* Xg = (const float*)d_in[1];
    const float* bw = (const float*)d_in[2];
    float* out = (float*)d_out;

    const int M = in_sizes[0] / 64;
    const int N = in_sizes[1] / 64;
    const float coeff = -logf((float)N) - logf(2.f * (float)M_PI) * 32.f;

    auto align256 = [](size_t v) { return (v + 255) & ~(size_t)255; };
    const size_t szXb   = align256((size_t)N * 64 * sizeof(short));
    const size_t szxb   = align256((size_t)M * 64 * sizeof(short));
    const size_t szEq   = align256((size_t)N * sizeof(float));
    const size_t szx2q  = align256((size_t)M * sizeof(float));
    const size_t szPart = align256((size_t)NSPLIT * M * sizeof(float));
    const size_t need   = szXb + szxb + szEq + szx2q + szPart;

    if (ws_size >= need && (M % MROWS) == 0) {
        char* w = (char*)d_ws;
        short* Xb   = (short*)(w);
        short* xb   = (short*)(w + szXb);
        float* Eq   = (float*)(w + szXb + szxb);
        float* x2q  = (float*)(w + szXb + szxb + szEq);
        float* part = (float*)(w + szXb + szxb + szEq + szx2q);

        const int totalRows = M + N;
        kde_prep<<<(totalRows * 8 + 255) / 256, 256, 0, stream>>>(
            x, Xg, bw, Xb, Eq, xb, x2q, M, N);

        const int NB = M / MROWS;
        kde_main6<<<NB * NSPLIT, 256, 0, stream>>>(Xb, Eq, xb, part, M, N, NB);

        kde_combine2<<<(M + 255) / 256, 256, 0, stream>>>(part, x2q, out, M, NSPLIT, coeff);
    } else {
        int nsplit = 8;
        if (ws_size < (size_t)nsplit * M * sizeof(float)) nsplit = 1;
        dim3 grid(M / 64, nsplit);
        kde_main_fb<<<grid, 256, 0, stream>>>(x, Xg, bw, (float*)d_ws, out, M, N, nsplit, coeff);
        if (nsplit > 1)
            kde_combine_fb<<<(M + 255) / 256, 256, 0, stream>>>((const float*)d_ws, out, M, nsplit, coeff);
    }
}

// Round 8
// 52.238 us; speedup vs baseline: 3.3569x; 1.0815x over previous
//
#include <hip/hip_runtime.h>
#include <hip/hip_bf16.h>
#include <math.h>

#define NSPLIT 16          // divisible by 8 for the XCD swizzle
#define MROWS  128

typedef __attribute__((ext_vector_type(8))) short short8;
typedef __attribute__((ext_vector_type(4))) float f32x4;

__device__ __forceinline__ short f2bf(float f) {
    __hip_bfloat16 h = __float2bfloat16(f);
    return __builtin_bit_cast(short, h);
}

// ---------------------------------------------------------------------------
// Preprocess:
//   X rows -> Xb bf16 (unscaled)  + Eq[col] = exp2(q*||X||^2)  (f32)
//   x rows -> xb bf16 scaled by -2q + x2q[row] = q*||x||^2     (f32)
// q = -log2(e)/(2 b^2).  exp(-d2/(2b^2)) = exp2(q*x2) * Eq[col] * exp2((-2q x)·X)
// ---------------------------------------------------------------------------
__global__ __launch_bounds__(256) void kde_prep(
    const float* __restrict__ x, const float* __restrict__ Xg,
    const float* __restrict__ bw,
    short* __restrict__ Xb, float* __restrict__ Eq,
    short* __restrict__ xb, float* __restrict__ x2q, int M, int N)
{
    const int gid = blockIdx.x * 256 + threadIdx.x;
    const int row = gid >> 3;
    const int sub = gid & 7;
    if (row >= M + N) return;

    const float b = bw[0];
    const float q = -1.4426950408889634f / (2.f * b * b);
    const float s2q = -2.f * q;

    const float* src;
    short* dst;
    float sc;
    if (row < N) { src = Xg + (size_t)row * 64;     dst = Xb + (size_t)row * 64;     sc = 1.f; }
    else         { src = x  + (size_t)(row-N) * 64; dst = xb + (size_t)(row-N) * 64; sc = s2q; }

    float4 v0 = ((const float4*)(src + sub * 8))[0];
    float4 v1 = ((const float4*)(src + sub * 8))[1];

    float ss = v0.x*v0.x + v0.y*v0.y + v0.z*v0.z + v0.w*v0.w
             + v1.x*v1.x + v1.y*v1.y + v1.z*v1.z + v1.w*v1.w;
    ss += __shfl_xor(ss, 1);
    ss += __shfl_xor(ss, 2);
    ss += __shfl_xor(ss, 4);

    short8 o;
    o[0]=f2bf(v0.x*sc); o[1]=f2bf(v0.y*sc); o[2]=f2bf(v0.z*sc); o[3]=f2bf(v0.w*sc);
    o[4]=f2bf(v1.x*sc); o[5]=f2bf(v1.y*sc); o[6]=f2bf(v1.z*sc); o[7]=f2bf(v1.w*sc);
    *(short8*)(dst + sub * 8) = o;

    if (sub == 0) {
        if (row < N) Eq[row] = exp2f(ss * q);
        else         x2q[row - N] = ss * q;
    }
}

// ---------------------------------------------------------------------------
// Main: 128 x-rows per block (8 rf fragments), 4 waves; each wave owns 16
// cols/iter -> block covers 64 cols/iter.
//
// 2-deep accumulator pipeline: iteration k's MFMAs write accB while the
// exp2/fma epilogue consumes accA produced by iteration k-1 (and vice
// versa). No same-iteration MFMA->exp dependency, so a single wave keeps
// the matrix pipe and the trans/VALU pipe simultaneously busy. No
// sched_barriers: phases are register-independent, scheduler is free.
//
// XCD-aware placement (round-7, kept): linear blockIdx L -> (split, mblock)
// so each XCD's resident blocks share 1-2 split chunks (~0.8 MB, L2-resident):
//   split  = (L & 7) + 8 * (L / (8*NB)),  mblock = (L >> 3) % NB
// ---------------------------------------------------------------------------
__global__ __launch_bounds__(256, 2) void kde_main7(
    const short* __restrict__ Xb, const float* __restrict__ Eq,
    const short* __restrict__ xb,
    float* __restrict__ partial, int M, int N, int NB)
{
    const int tid  = threadIdx.x;
    const int lane = tid & 63;
    const int wave = tid >> 6;
    const int l15  = lane & 15;
    const int kq   = lane >> 4;

    const int L      = blockIdx.x;
    const int split  = (L & 7) + 8 * (L / (8 * NB));
    const int mblock = (L >> 3) % NB;
    const int rowbase = mblock * MROWS;

    const int T    = (N + 63) >> 6;           // total 64-col iterations
    const int base = T / NSPLIT;
    const int remu = T % NSPLIT;
    const int it0  = split * base + min(split, remu);
    const int cnt  = base + (split < remu ? 1 : 0);
    const bool maskedLast = (it0 + cnt == T) && ((N & 63) != 0);
    const int nfull = cnt - (maskedLast ? 1 : 0);

    // A fragments (bf16, pre-scaled by -2q): row = lane&15, k = 8*(lane>>4)+i
    short8 afrag[8][2];
    #pragma unroll
    for (int rf = 0; rf < 8; ++rf) {
        const short* p = xb + (size_t)(rowbase + rf*16 + l15) * 64 + kq * 8;
        afrag[rf][0] = *(const short8*)(p);
        afrag[rf][1] = *(const short8*)(p + 32);
    }

    const f32x4 zero4 = {0.f, 0.f, 0.f, 0.f};

    float s[8][4];
    #pragma unroll
    for (int rf = 0; rf < 8; ++rf)
        #pragma unroll
        for (int r = 0; r < 4; ++r) s[rf][r] = 0.f;

    // streaming pointers (per-iter stride: 64 cols)
    const short* pB = Xb + (size_t)(it0*64 + wave*16 + l15) * 64 + kq * 8;
    const float* pE = Eq + it0*64 + wave*16 + l15;
    const size_t strideB = (size_t)64 * 64;

    f32x4 accA[8], accB[8];
    short8 Ba0, Ba1, Bb0, Bb1;
    float  Ea, Eb;

    auto LOADA = [&]() {
        Ba0 = *(const short8*)(pB);
        Ba1 = *(const short8*)(pB + 32);
        Ea  = *pE;
        pB += strideB; pE += 64;
    };
    auto LOADB = [&]() {
        Bb0 = *(const short8*)(pB);
        Bb1 = *(const short8*)(pB + 32);
        Eb  = *pE;
        pB += strideB; pE += 64;
    };

    // MFMA into dst, interleaved with exp/fma consuming src (prev iter).
    auto MFMA_EXP = [&](short8 B0, short8 B1, f32x4 (&dst)[8],
                        const f32x4 (&src)[8], float E) {
        #pragma unroll
        for (int rf = 0; rf < 8; ++rf) {
            f32x4 a = __builtin_amdgcn_mfma_f32_16x16x32_bf16(afrag[rf][0], B0, zero4, 0, 0, 0);
            dst[rf]  = __builtin_amdgcn_mfma_f32_16x16x32_bf16(afrag[rf][1], B1, a, 0, 0, 0);
            #pragma unroll
            for (int r = 0; r < 4; ++r)
                s[rf][r] = fmaf(E, __builtin_amdgcn_exp2f(src[rf][r]), s[rf][r]);
        }
    };
    auto MFMA_ONLY = [&](short8 B0, short8 B1, f32x4 (&dst)[8]) {
        #pragma unroll
        for (int rf = 0; rf < 8; ++rf) {
            f32x4 a = __builtin_amdgcn_mfma_f32_16x16x32_bf16(afrag[rf][0], B0, zero4, 0, 0, 0);
            dst[rf]  = __builtin_amdgcn_mfma_f32_16x16x32_bf16(afrag[rf][1], B1, a, 0, 0, 0);
        }
    };
    auto EXP_ONLY = [&](const f32x4 (&src)[8], float E) {
        #pragma unroll
        for (int rf = 0; rf < 8; ++rf)
            #pragma unroll
            for (int r = 0; r < 4; ++r)
                s[rf][r] = fmaf(E, __builtin_amdgcn_exp2f(src[rf][r]), s[rf][r]);
    };

    if (nfull > 0) {
        LOADA();                      // iter 0 -> bufA
        if (nfull > 1) LOADB();       // iter 1 -> bufB (prefetch)
        MFMA_ONLY(Ba0, Ba1, accA);    // process iter 0 (prologue stall ok)
        float EAc = Ea;

        int it = 1;
        for (; it + 1 < nfull; it += 2) {
            LOADA();                              // prefetch iter it+1 -> bufA
            MFMA_EXP(Bb0, Bb1, accB, accA, EAc);  // process iter it; drain accA
            float EBc = Eb;
            if (it + 2 < nfull) LOADB();          // prefetch iter it+2 -> bufB
            MFMA_EXP(Ba0, Ba1, accA, accB, EBc);  // process iter it+1; drain accB
            EAc = Ea;
        }
        if (it < nfull) {                         // one remaining full iter (in bufB)
            MFMA_EXP(Bb0, Bb1, accB, accA, EAc);
            EXP_ONLY(accB, Eb);
        } else {
            EXP_ONLY(accA, EAc);
        }
    }

    // masked tail (single global-last iteration, if ragged) — sequential
    if (maskedLast) {
        const int col = (it0 + cnt - 1)*64 + wave*16 + l15;
        const int c   = min(col, N - 1);
        const short* p = Xb + (size_t)c * 64 + kq * 8;
        Ba0 = *(const short8*)(p);
        Ba1 = *(const short8*)(p + 32);
        Ea  = (col < N) ? Eq[c] : 0.f;
        MFMA_ONLY(Ba0, Ba1, accA);
        EXP_ONLY(accA, Ea);
    }

    // reduce across the 16 lanes holding cols
    float t[8][4];
    #pragma unroll
    for (int rf = 0; rf < 8; ++rf)
        #pragma unroll
        for (int r = 0; r < 4; ++r) {
            float v = s[rf][r];
            v += __shfl_xor(v, 1);
            v += __shfl_xor(v, 2);
            v += __shfl_xor(v, 4);
            v += __shfl_xor(v, 8);
            t[rf][r] = v;
        }

    __shared__ float red[4][MROWS];
    if (l15 == 0) {
        #pragma unroll
        for (int rf = 0; rf < 8; ++rf)
            #pragma unroll
            for (int r = 0; r < 4; ++r)
                red[wave][rf*16 + kq*4 + r] = t[rf][r];
    }
    __syncthreads();
    if (tid < MROWS) {
        partial[(size_t)split * M + rowbase + tid] =
            red[0][tid] + red[1][tid] + red[2][tid] + red[3][tid];
    }
}

__global__ __launch_bounds__(256) void kde_combine2(
    const float* __restrict__ ws, const float* __restrict__ x2q,
    float* __restrict__ out, int M, int nsplit, float coeff)
{
    int i = blockIdx.x * 256 + threadIdx.x;
    if (i < M) {
        float t = 0.f;
        for (int s = 0; s < nsplit; ++s) t += ws[(size_t)s * M + i];
        out[i] = fmaf(0.6931471805599453f, x2q[i], logf(t) + coeff);
    }
}

// ---------------------------------------------------------------------------
// Fallback fused fp32 path (only if ws too small or M not tile-divisible).
// ---------------------------------------------------------------------------
__global__ __launch_bounds__(256) void kde_main_fb(
    const float* __restrict__ x, const float* __restrict__ Xg,
    const float* __restrict__ bw, float* __restrict__ ws,
    float* __restrict__ out, int M, int N, int nsplit, float coeff)
{
    const int tid  = threadIdx.x;
    const int lane = tid & 63;
    const int wave = tid >> 6;
    const int l15  = lane & 15;
    const int kq   = lane >> 4;
    const int rowbase = blockIdx.x * 64;
    const int split   = blockIdx.y;
    const int chunk   = (N + nsplit - 1) / nsplit;
    const int colstart = split * chunk;
    const int colend   = min(colstart + chunk, N);

    __shared__ float lds_x2[64];
    __shared__ float red[4][64];

    if (tid < 64) {
        const float* xp = x + (size_t)(rowbase + tid) * 64;
        float ssum = 0.f;
        #pragma unroll
        for (int k = 0; k < 16; ++k) {
            float4 v = ((const float4*)xp)[k];
            ssum += v.x*v.x + v.y*v.y + v.z*v.z + v.w*v.w;
        }
        lds_x2[tid] = ssum;
    }

    short8 afrag[4][2];
    #pragma unroll
    for (int rf = 0; rf < 4; ++rf) {
        const float* xp = x + (size_t)(rowbase + rf*16 + l15) * 64;
        #pragma unroll
        for (int kf = 0; kf < 2; ++kf) {
            const float* p = xp + kf*32 + kq*8;
            float4 v0 = ((const float4*)p)[0];
            float4 v1 = ((const float4*)p)[1];
            short8 a;
            a[0]=f2bf(v0.x); a[1]=f2bf(v0.y); a[2]=f2bf(v0.z); a[3]=f2bf(v0.w);
            a[4]=f2bf(v1.x); a[5]=f2bf(v1.y); a[6]=f2bf(v1.z); a[7]=f2bf(v1.w);
            afrag[rf][kf] = a;
        }
    }
    __syncthreads();

    float xa[4][4];
    #pragma unroll
    for (int rf = 0; rf < 4; ++rf)
        #pragma unroll
        for (int r = 0; r < 4; ++r)
            xa[rf][r] = lds_x2[rf*16 + kq*4 + r];

    const float b = bw[0];
    const float q = -1.4426950408889634f / (2.f * b * b);

    float s[4][4];
    #pragma unroll
    for (int rf = 0; rf < 4; ++rf)
        #pragma unroll
        for (int r = 0; r < 4; ++r) s[rf][r] = 0.f;

    const int span  = colend - colstart;
    const int niter = (span + 63) / 64;

    for (int it = 0; it < niter; ++it) {
        const int col  = colstart + it*64 + wave*16 + l15;
        const int colc = min(col, N - 1);
        const bool valid = (col < colend);

        const float* Xp = Xg + (size_t)colc * 64;
        float4 v0 = ((const float4*)(Xp + kq*8))[0];
        float4 v1 = ((const float4*)(Xp + kq*8))[1];
        float4 v2 = ((const float4*)(Xp + 32 + kq*8))[0];
        float4 v3 = ((const float4*)(Xp + 32 + kq*8))[1];

        float pa = v0.x*v0.x + v0.y*v0.y + v0.z*v0.z + v0.w*v0.w
                 + v1.x*v1.x + v1.y*v1.y + v1.z*v1.z + v1.w*v1.w
                 + v2.x*v2.x + v2.y*v2.y + v2.z*v2.z + v2.w*v2.w
                 + v3.x*v3.x + v3.y*v3.y + v3.z*v3.z + v3.w*v3.w;
        pa += __shfl_xor(pa, 16);
        pa += __shfl_xor(pa, 32);

        short8 bb0, bb1;
        bb0[0]=f2bf(v0.x); bb0[1]=f2bf(v0.y); bb0[2]=f2bf(v0.z); bb0[3]=f2bf(v0.w);
        bb0[4]=f2bf(v1.x); bb0[5]=f2bf(v1.y); bb0[6]=f2bf(v1.z); bb0[7]=f2bf(v1.w);
        bb1[0]=f2bf(v2.x); bb1[1]=f2bf(v2.y); bb1[2]=f2bf(v2.z); bb1[3]=f2bf(v2.w);
        bb1[4]=f2bf(v3.x); bb1[5]=f2bf(v3.y); bb1[6]=f2bf(v3.z); bb1[7]=f2bf(v3.w);

        #pragma unroll
        for (int rf = 0; rf < 4; ++rf) {
            f32x4 acc = {0.f, 0.f, 0.f, 0.f};
            acc = __builtin_amdgcn_mfma_f32_16x16x32_bf16(afrag[rf][0], bb0, acc, 0, 0, 0);
            acc = __builtin_amdgcn_mfma_f32_16x16x32_bf16(afrag[rf][1], bb1, acc, 0, 0, 0);
            #pragma unroll
            for (int r = 0; r < 4; ++r) {
                float d2 = fmaxf(xa[rf][r] + pa - 2.f*acc[r], 0.f);
                float e = valid ? __builtin_amdgcn_exp2f(d2 * q) : 0.f;
                s[rf][r] += e;
            }
        }
    }

    #pragma unroll
    for (int rf = 0; rf < 4; ++rf)
        #pragma unroll
        for (int r = 0; r < 4; ++r) {
            float v = s[rf][r];
            v += __shfl_xor(v, 1);
            v += __shfl_xor(v, 2);
            v += __shfl_xor(v, 4);
            v += __shfl_xor(v, 8);
            s[rf][r] = v;
        }

    __syncthreads();
    if (l15 == 0) {
        #pragma unroll
        for (int rf = 0; rf < 4; ++rf)
            #pragma unroll
            for (int r = 0; r < 4; ++r)
                red[wave][rf*16 + kq*4 + r] = s[rf][r];
    }
    __syncthreads();

    if (tid < 64) {
        float tot = red[0][tid] + red[1][tid] + red[2][tid] + red[3][tid];
        if (nsplit == 1) out[rowbase + tid] = logf(tot) + coeff;
        else             ws[(size_t)split * M + rowbase + tid] = tot;
    }
}

__global__ __launch_bounds__(256) void kde_combine_fb(
    const float* __restrict__ ws, float* __restrict__ out,
    int M, int nsplit, float coeff)
{
    int i = blockIdx.x * 256 + threadIdx.x;
    if (i < M) {
        float t = 0.f;
        for (int s = 0; s < nsplit; ++s) t += ws[(size_t)s * M + i];
        out[i] = logf(t) + coeff;
    }
}

extern "C" void kernel_launch(void* const* d_in, const int* in_sizes, int n_in,
                              void* d_out, int out_size, void* d_ws, size_t ws_size,
                              hipStream_t stream) {
    const float* x  = (const float*)d_in[0];
    const float* Xg = (const float*)d_in[1];
    const float* bw = (const float*)d_in[2];
    float* out = (float*)d_out;

    const int M = in_sizes[0] / 64;
    const int N = in_sizes[1] / 64;
    const float coeff = -logf((float)N) - logf(2.f * (float)M_PI) * 32.f;

    auto align256 = [](size_t v) { return (v + 255) & ~(size_t)255; };
    const size_t szXb   = align256((size_t)N * 64 * sizeof(short));
    const size_t szxb   = align256((size_t)M * 64 * sizeof(short));
    const size_t szEq   = align256((size_t)N * sizeof(float));
    const size_t szx2q  = align256((size_t)M * sizeof(float));
    const size_t szPart = align256((size_t)NSPLIT * M * sizeof(float));
    const size_t need   = szXb + szxb + szEq + szx2q + szPart;

    if (ws_size >= need && (M % MROWS) == 0) {
        char* w = (char*)d_ws;
        short* Xb   = (short*)(w);
        short* xb   = (short*)(w + szXb);
        float* Eq   = (float*)(w + szXb + szxb);
        float* x2q  = (float*)(w + szXb + szxb + szEq);
        float* part = (float*)(w + szXb + szxb + szEq + szx2q);

        const int totalRows = M + N;
        kde_prep<<<(totalRows * 8 + 255) / 256, 256, 0, stream>>>(
            x, Xg, bw, Xb, Eq, xb, x2q, M, N);

        const int NB = M / MROWS;
        kde_main7<<<NB * NSPLIT, 256, 0, stream>>>(Xb, Eq, xb, part, M, N, NB);

        kde_combine2<<<(M + 255) / 256, 256, 0, stream>>>(part, x2q, out, M, NSPLIT, coeff);
    } else {
        int nsplit = 8;
        if (ws_size < (size_t)nsplit * M * sizeof(float)) nsplit = 1;
        dim3 grid(M / 64, nsplit);
        kde_main_fb<<<grid, 256, 0, stream>>>(x, Xg, bw, (float*)d_ws, out, M, N, nsplit, coeff);
        if (nsplit > 1)
            kde_combine_fb<<<(M + 255) / 256, 256, 0, stream>>>((const float*)d_ws, out, M, nsplit, coeff);
    }
}